// Round 9
// baseline (436.194 us; speedup 1.0000x reference)
//
#include <hip/hip_runtime.h>
#include <hip/hip_bf16.h>

#define EPS 1e-5f

// ---- problem dims ----
#define BB 2
#define NV 12000
#define NP 32
#define CIN 5
#define GD 20
// conv1: active out 10x11x11; conv2 region 5x6x6; conv3 region 3x4x4

typedef __attribute__((ext_vector_type(8))) short bf16x8;
typedef __attribute__((ext_vector_type(4))) float f32x4;

// ---- workspace layout (float offsets) ----
static const size_t OFF_SX   = 0;         // 32
static const size_t OFF_MST  = 32;        // 4160   [memset0: 0..4192]
static const size_t OFF_AC1  = 4192;      // 128
static const size_t OFF_AC2  = 4320;      // 256
static const size_t OFF_ACB1 = 4576;      // 384  (A[128],C[128],bg1[128])
static const size_t OFF_ACB2 = 4960;      // 2560 (A[256],C[256],bgn2[256*8])
static const size_t OFF_AC3  = 7520;      // 512
static const size_t OFF_BG2  = 8032;      // 2048   [memset1: 8032..13152]
static const size_t OFF_BG3  = 10080;     // 3072
static const size_t OFF_W2T  = 13152;     // 8192
static const size_t OFF_WIN  = 21344;     // 16000 ints [memset 0xFF]
static const size_t OFF_F1   = 37344;     // 1,536,000
static const size_t OFF_I0CL = 1573344;   // bf16 [b][21][23][24][128ci] (+slack) = 1,485,824 floats (memset 0)
static const size_t OFF_I1   = 3059168;   // 585,728   [b][ci][11][13][16]
static const size_t OFF_I2   = 3644896;   // 387,072   [b][ci][7][9][12]
static const size_t OFF_WT1B = 4031968;   // bf16 [27][128co][128ci] = 221,184 floats
static const size_t OFF_WT2  = 4253152;   // 884,736
static const size_t OFF_WT3  = 5137888;   // 1,769,472
static const size_t OFF_RAW1 = 6907360;   // 4 x 309,760
static const size_t OFF_RAW2 = 8146400;   // 16 x 92,160
static const size_t OFF_RAW3 = 9620960;   // 32 x 24,576
// end = 10,407,392 floats = 41.6 MB

// ================= VFE stage =================

// vectorized: one thread per 4-point group (5 float4 loads = 80B contiguous)
__global__ __launch_bounds__(256) void k_stats_x(const float* __restrict__ vf, float* __restrict__ out) {
    float ls[5] = {0,0,0,0,0};
    float lq[15];
    #pragma unroll
    for (int i=0;i<15;i++) lq[i]=0.f;
    const int ng = (BB*NV*NP)/4;   // 192,000 groups
    for (int g = blockIdx.x*blockDim.x + threadIdx.x; g < ng; g += gridDim.x*blockDim.x) {
        float xx[20];
        const float4* x4 = (const float4*)(vf + (size_t)g*20);
        #pragma unroll
        for (int i=0;i<5;i++){ float4 t = x4[i]; xx[4*i]=t.x; xx[4*i+1]=t.y; xx[4*i+2]=t.z; xx[4*i+3]=t.w; }
        #pragma unroll
        for (int p=0;p<4;p++){
            const float* v = xx + p*5;
            int k=0;
            #pragma unroll
            for (int c=0;c<5;c++){
                ls[c]+=v[c];
                #pragma unroll
                for(int c2=c;c2<5;c2++){ lq[k++]+=v[c]*v[c2]; }
            }
        }
    }
    __shared__ float sh[20];
    if (threadIdx.x < 20) sh[threadIdx.x]=0.f;
    __syncthreads();
    #pragma unroll
    for (int c=0;c<5;c++) atomicAdd(&sh[c], ls[c]);
    #pragma unroll
    for (int k=0;k<15;k++) atomicAdd(&sh[5+k], lq[k]);
    __syncthreads();
    if (threadIdx.x<20) atomicAdd(&out[threadIdx.x], sh[threadIdx.x]);
}

__global__ void k_ac1(const float* __restrict__ stats, const float* __restrict__ w1,
                      const float* __restrict__ b1, const float* __restrict__ g1,
                      const float* __restrict__ be1, float* __restrict__ AC1){
    int o = threadIdx.x; if (o>=64) return;
    const float N = (float)(BB*NV*NP);
    float w[5];
    #pragma unroll
    for(int c=0;c<5;c++) w[c]=w1[o*5+c];
    float b=b1[o];
    float wd=0;
    #pragma unroll
    for(int c=0;c<5;c++) wd += w[c]*stats[c];
    float m = wd/N + b;
    float q=0; int kk=5;
    for(int c=0;c<5;c++) for(int c2=c;c2<5;c2++){ float s=stats[kk++]; q += (c==c2?1.f:2.f)*w[c]*w[c2]*s; }
    q = q/N + 2.f*b*wd/N + b*b;
    float var = q - m*m;
    float A = g1[o]*rsqrtf(var + EPS);
    AC1[o] = A;
    AC1[64+o] = be1[o] + (b - m)*A;
}

__global__ __launch_bounds__(256) void k_vfe1(const float* __restrict__ vf, const float* __restrict__ w1,
                                              const float* __restrict__ AC1, float* __restrict__ f1){
    int wave = threadIdx.x >> 6;
    int lane = threadIdx.x & 63;
    int v = blockIdx.x*4 + wave;
    if (v >= BB*NV) return;
    float w[5];
    #pragma unroll
    for (int c=0;c<5;c++) w[c] = w1[lane*5+c];
    float A = AC1[lane], Cc = AC1[64+lane];
    const float* x = vf + (size_t)v*(NP*CIN);
    float mx = -1e30f;
    #pragma unroll
    for (int pc = 0; pc < 8; pc++) {
        float xx[20];
        const float4* x4 = (const float4*)(x + pc*20);
        #pragma unroll
        for (int i=0;i<5;i++){ float4 t = x4[i]; xx[4*i]=t.x; xx[4*i+1]=t.y; xx[4*i+2]=t.z; xx[4*i+3]=t.w; }
        #pragma unroll
        for (int j=0;j<4;j++){
            float y = xx[j*5]*w[0]+xx[j*5+1]*w[1]+xx[j*5+2]*w[2]+xx[j*5+3]*w[3]+xx[j*5+4]*w[4];
            mx = fmaxf(mx, y*A + Cc);
        }
    }
    f1[(size_t)v*64 + lane] = fmaxf(mx, 0.f);
}

__global__ __launch_bounds__(256) void k_stats_f1(const float* __restrict__ f1, float* __restrict__ Mst){
    __shared__ float tile[16][64];
    __shared__ float ssum[64];
    int t = threadIdx.x;
    if (t < 64) ssum[t]=0.f;
    float acc[4][4];
    #pragma unroll
    for(int i=0;i<4;i++)
        #pragma unroll
        for(int j=0;j<4;j++) acc[i][j]=0.f;
    int i4 = (t>>4)*4, j4 = (t&15)*4;
    const int NT = (BB*NV)/16; // 1500
    for (int tl = blockIdx.x; tl < NT; tl += gridDim.x) {
        __syncthreads();
        for (int i = t; i < 16*64; i += 256) tile[i>>6][i&63] = f1[(size_t)tl*1024 + i];
        __syncthreads();
        #pragma unroll
        for (int r=0;r<16;r++){
            float a[4], bb[4];
            #pragma unroll
            for (int u=0;u<4;u++) a[u]=tile[r][i4+u];
            #pragma unroll
            for (int u=0;u<4;u++) bb[u]=tile[r][j4+u];
            #pragma unroll
            for (int u=0;u<4;u++)
                #pragma unroll
                for (int q=0;q<4;q++) acc[u][q] += a[u]*bb[q];
        }
        if (t < 64) {
            float s=0;
            #pragma unroll
            for(int r=0;r<16;r++) s+=tile[r][t];
            ssum[t]+=s;
        }
    }
    #pragma unroll
    for(int i=0;i<4;i++)
        #pragma unroll
        for(int j=0;j<4;j++) atomicAdd(&Mst[(size_t)(i4+i)*64 + (j4+j)], acc[i][j]);
    __syncthreads();
    if (t<64) atomicAdd(&Mst[4096 + t], ssum[t]);
}

// parallel ac2: one block per o (128 blocks x 64 lanes)
__global__ __launch_bounds__(64) void k_ac2(const float* __restrict__ Mst, const float* __restrict__ w2,
                                            const float* __restrict__ b2, const float* __restrict__ g2,
                                            const float* __restrict__ be2, float* __restrict__ AC2){
    int o = blockIdx.x;
    int j = threadIdx.x;
    const float N = (float)(BB*NV);
    const float* M = Mst; const float* sv = Mst+4096;
    const float* wrow = w2 + o*64;
    float wj = wrow[j];
    float sj = 0.f;
    #pragma unroll 8
    for (int c=0;c<64;c++) sj += wrow[c]*M[c*64+j];
    float q = wj*sj;
    float wdp = wj*sv[j];
    #pragma unroll
    for (int off=32; off>0; off>>=1){ q += __shfl_down(q,off); wdp += __shfl_down(wdp,off); }
    if (j==0){
        float b = b2[o];
        float m = wdp/N + b;
        float qq = q/N + 2.f*b*wdp/N + b*b;
        float var = qq - m*m;
        float A = g2[o]*rsqrtf(var+EPS);
        AC2[o]=A; AC2[128+o]= be2[o] + (b-m)*A;
    }
}

// ================= scatter =================

__global__ void k_scatter(const int* __restrict__ coords, int* __restrict__ winner){
    int i = blockIdx.x*blockDim.x+threadIdx.x;
    if (i >= BB*NV) return;
    int b = i / NV, n = i % NV;
    int d = coords[(size_t)i*3], h = coords[(size_t)i*3+1], w = coords[(size_t)i*3+2];
    if (d<0||d>=GD||h<0||h>=GD||w<0||w>=GD) return;
    atomicMax(&winner[b*8000 + d*400 + h*20 + w], n);
}

// FUSED vfe2 + scatter-fill into channels-last bf16 I0cl[b][21][23][24][128].
__global__ __launch_bounds__(256) void k_I0(const int* __restrict__ winner, const float* __restrict__ f1,
                                            const float* __restrict__ w2T, const float* __restrict__ AC2,
                                            __hip_bfloat16* __restrict__ I0cl){
    int blk = blockIdx.x;
    int b = blk / 400; int dh = blk % 400;
    int d = dh / 20, h = dh % 20;
    __shared__ int win[20];
    __shared__ float f1sh[20][64];
    __shared__ float sh[20*128];   // [w][ci]
    int t = threadIdx.x;
    if (t < 20) win[t] = winner[b*8000 + dh*20 + t];
    __syncthreads();
    for (int idx = t; idx < 1280; idx += 256){
        int cell = idx >> 6, c = idx & 63;
        int n = win[cell];
        f1sh[cell][c] = (n>=0) ? f1[((size_t)(b*NV+n))*64 + c] : 0.f;
    }
    __syncthreads();
    int o = t & 127;
    int half = t >> 7;
    float A = AC2[o], C = AC2[128+o];
    for (int p=0;p<10;p++){
        int cell = p*2 + half;
        float acc = 0.f;
        if (win[cell] >= 0){
            #pragma unroll
            for (int c=0;c<64;c++) acc += f1sh[cell][c]*w2T[c*128+o];
            acc = fmaxf(acc*A + C, 0.f);
        }
        sh[cell*128 + o] = acc;
    }
    __syncthreads();
    __hip_bfloat16* outp = I0cl + (((size_t)(b*21 + d+1)*23 + h+1)*24 + 1)*128;
    for (int idx = t; idx < 2560; idx += 256) outp[idx] = __float2bfloat16(sh[idx]);
}

// ================= merged weight prep =================
// blocks 0..215: wT2 tiles; 216..647: wT3 tiles; 648: w2T; 649..776: wT1b (bf16 pack, co = blk-649)
__global__ __launch_bounds__(256) void k_t_tile(const float* __restrict__ cw2, const float* __restrict__ cw3,
                                                const float* __restrict__ w2, const float* __restrict__ cw1,
                                                float* __restrict__ wT2, float* __restrict__ wT3,
                                                float* __restrict__ w2T, __hip_bfloat16* __restrict__ wT1b){
    int blk = blockIdx.x;
    if (blk >= 649){
        int co = blk - 649;
        __shared__ float tlw[3456];
        int t = threadIdx.x;
        for (int j=t; j<3456; j+=256) tlw[j] = cw1[(size_t)co*3456 + j];   // j = ci*27+tap
        __syncthreads();
        for (int idx=t; idx<3456; idx+=256){
            int tap = idx >> 7, ci = idx & 127;
            wT1b[((size_t)(tap*128 + co) << 7) + ci] = __float2bfloat16(tlw[ci*27 + tap]);
        }
        return;
    }
    if (blk == 648){
        for (int i=threadIdx.x; i<8192; i+=256){ int o=i>>6, c=i&63; w2T[c*128+o]=w2[i]; }
        return;
    }
    const float* src; float* dst; int CO, R;
    if (blk < 216){ src=cw2; dst=wT2; CO=256; R=3456; }
    else { blk-=216; src=cw3; dst=wT3; CO=256; R=6912; }
    int nrt = R/64;
    int rt = blk % nrt, ct = blk / nrt;
    int r0 = rt*64, c0 = ct*64;
    __shared__ float tl[64][65];
    int tj = threadIdx.x & 63;
    int ti0 = threadIdx.x >> 6;
    #pragma unroll
    for (int k=0;k<16;k++){
        int i = ti0 + k*4;
        tl[i][tj] = src[(size_t)(c0+i)*R + r0 + tj];
    }
    __syncthreads();
    #pragma unroll
    for (int k=0;k<16;k++){
        int j = ti0 + k*4;
        dst[(size_t)(r0+j)*CO + c0 + tj] = tl[tj][j];
    }
}

// ================= conv1 via MFMA (bf16 implicit GEMM) =================
// grid 1760 = ((b*10+od)*11+oh)*8 + coq ; 4 waves = kq (K-slices of 32 ci); each wave 27 MFMA.
__global__ __launch_bounds__(256) void k_conv1m(const __hip_bfloat16* __restrict__ I0cl,
                                                const __hip_bfloat16* __restrict__ wT1b,
                                                float* __restrict__ raw1){
    int blk = blockIdx.x;
    int coq = blk & 7; blk >>= 3;
    int oh = blk % 11; blk /= 11;
    int od = blk % 10; int b = blk / 10;
    int kq = threadIdx.x >> 6, lane = threadIdx.x & 63;
    int col = lane & 15, quad = lane >> 4;
    int co0 = coq*16;
    int ci_base = kq*32 + quad*8;
    f32x4 acc = {0.f,0.f,0.f,0.f};
    const __hip_bfloat16* Bb = I0cl + (size_t)b*21*23*24*128 + (2*col)*128 + ci_base;
    const __hip_bfloat16* Ab = wT1b + (size_t)(co0 + col)*128 + ci_base;
    #pragma unroll 3
    for (int tap=0; tap<27; tap++){
        int kd = tap/9, kh = (tap/3)%3, kw = tap%3;
        int d = 2*od + kd, h = 2*oh + kh;     // padded indices
        const __hip_bfloat16* bp = Bb + ((size_t)(d*23 + h)*24 + kw)*128;
        const __hip_bfloat16* ap = Ab + (size_t)tap*16384;
        bf16x8 a0 = *(const bf16x8*)ap;
        bf16x8 b0 = *(const bf16x8*)bp;
        acc = __builtin_amdgcn_mfma_f32_16x16x32_bf16(a0, b0, acc, 0, 0, 0);
    }
    if (col < 11){
        #pragma unroll
        for (int r=0;r<4;r++){
            int co = co0 + quad*4 + r;
            raw1[(size_t)kq*309760 + (((size_t)(b*128+co)*10 + od)*11 + oh)*11 + col] = acc[r];
        }
    }
}

// stats for conv1 (zero background), sums 4 K-split buffers
__global__ __launch_bounds__(256) void k_stats_c1(const float* __restrict__ raw1, const float* __restrict__ cb,
                                                  const float* __restrict__ cg, const float* __restrict__ cbe,
                                                  float* __restrict__ ACb1){
    int co = blockIdx.x;
    float s=0, ss=0;
    for (int b=0;b<2;b++){
        size_t base = ((size_t)(b*128+co))*1210;
        for (int i=threadIdx.x; i<1210; i+=256){
            float v = raw1[base+i] + raw1[309760+base+i] + raw1[2*309760+base+i] + raw1[3*309760+base+i];
            s+=v; ss+=v*v;
        }
    }
    __shared__ float sh1[256], sh2[256];
    sh1[threadIdx.x]=s; sh2[threadIdx.x]=ss; __syncthreads();
    for (int st=128; st>0; st>>=1){
        if (threadIdx.x<st){ sh1[threadIdx.x]+=sh1[threadIdx.x+st]; sh2[threadIdx.x]+=sh2[threadIdx.x+st]; }
        __syncthreads();
    }
    if (threadIdx.x==0){
        float bias = cb[co];
        const float N = 81920.f;   // 2*10*64*64
        float sum_y = sh1[0] + N*bias;
        float ssq_y = sh2[0] + 2.f*bias*sh1[0] + N*bias*bias;
        float m = sum_y/N;
        float var = ssq_y/N - m*m;
        float A = cg[co]*rsqrtf(var+EPS);
        float C = cbe[co] - m*A;
        ACb1[co]=A; ACb1[128+co]=C;
        ACb1[256+co]=fmaxf(bias*A + C, 0.f);  // bg1
    }
}

// I1p[b][ci][11][13][16]
__global__ void k_fill_I1(const float* __restrict__ raw1, const float* __restrict__ ACb1,
                          const float* __restrict__ cb, float* __restrict__ I1p){
    int i = blockIdx.x*blockDim.x + threadIdx.x;   // grid exactly 585,728
    int wpad = i % 16; int r = i / 16;
    int hpad = r % 13; r /= 13;
    int dpad = r % 11; r /= 11;
    int ci = r % 128; int b = r / 128;
    float val;
    if (dpad==0 || hpad==0 || wpad==0 || wpad>12) val = 0.f;
    else {
        int d = dpad-1, h = hpad-1, w = wpad-1;
        if (h < 11 && w < 11){
            size_t idx = (((size_t)(b*128+ci)*10 + d)*11 + h)*11 + w;
            float raw = raw1[idx] + raw1[309760+idx] + raw1[2*309760+idx] + raw1[3*309760+idx];
            val = fmaxf((raw + cb[ci])*ACb1[ci] + ACb1[128+ci], 0.f);
        } else val = ACb1[256+ci];
    }
    I1p[i] = val;
}

// conv2 background class constants: bgraw2[o][8]; coalesced via wT2
__global__ __launch_bounds__(256) void k_bg2(const float* __restrict__ wT2, const float* __restrict__ ACb1,
                                             float* __restrict__ bgraw2){
    int o = threadIdx.x;
    int ci0 = blockIdx.x*8;
    float acc[8];
    #pragma unroll
    for (int c=0;c<8;c++) acc[c]=0.f;
    for (int ci=ci0; ci<ci0+8; ci++){
        float w[27];
        const float* wp = wT2 + (size_t)ci*27*256 + o;
        #pragma unroll
        for (int t=0;t<27;t++) w[t] = wp[t*256];
        float bg = ACb1[256+ci];
        float sw0[9], sw1[9];
        #pragma unroll
        for (int t9=0;t9<9;t9++){ sw1[t9]=w[3*t9+1]+w[3*t9+2]; sw0[t9]=w[3*t9]+sw1[t9]; }
        #pragma unroll
        for (int cls=0; cls<8; cls++){
            const int d0=(cls>>2)&1, h0=(cls>>1)&1, w0=cls&1;
            float ws=0.f;
            #pragma unroll
            for (int kd=0;kd<3;kd++){
                if (d0 && kd==0) continue;
                #pragma unroll
                for (int kh=0;kh<3;kh++){
                    if (h0 && kh==0) continue;
                    ws += w0 ? sw1[kd*3+kh] : sw0[kd*3+kh];
                }
            }
            acc[cls] += bg*ws;
        }
    }
    #pragma unroll
    for (int cls=0;cls<8;cls++) atomicAdd(&bgraw2[o*8+cls], acc[cls]);
}

// conv2: grid 960 = ((b*5+od)*6+oh)*16+ciq ; 256 thr = 4 waves x 2 ci; LDS reduce -> store buf[ciq]
__global__ __launch_bounds__(256) void k_conv2(const float* __restrict__ I1p, const float* __restrict__ wT2,
                                               float* __restrict__ raw2){
    int blk = blockIdx.x;
    int ciq = blk & 15; blk >>= 4;
    int oh = blk % 6; blk /= 6;
    int od = blk % 5; int b = blk / 5;
    int wave = threadIdx.x >> 6, lane = threadIdx.x & 63;
    float acc[4][6];
    #pragma unroll
    for (int q=0;q<4;q++)
        #pragma unroll
        for (int i=0;i<6;i++) acc[q][i]=0.f;
    int ci0 = ciq*8 + wave*2;
    for (int ci = ci0; ci < ci0+2; ci++){
        const float* base = I1p + ((size_t)(b*128+ci)*11 + 2*od)*208 + (2*oh)*16;
        const float* wp0 = wT2 + (size_t)ci*27*256 + lane;
        #pragma unroll
        for (int kd=0;kd<3;kd++){
            #pragma unroll
            for (int kh=0;kh<3;kh++){
                float row[16];
                const float4* rp = (const float4*)(base + kd*208 + kh*16);
                #pragma unroll
                for (int i=0;i<4;i++){ float4 t=rp[i]; row[4*i]=t.x; row[4*i+1]=t.y; row[4*i+2]=t.z; row[4*i+3]=t.w; }
                const float* wp = wp0 + (kd*3+kh)*3*256;
                #pragma unroll
                for (int kw=0;kw<3;kw++){
                    float w0=wp[kw*256], w1=wp[kw*256+64], w2v=wp[kw*256+128], w3=wp[kw*256+192];
                    #pragma unroll
                    for (int ow=0;ow<6;ow++){
                        float x = row[2*ow+kw];
                        acc[0][ow]+=x*w0; acc[1][ow]+=x*w1; acc[2][ow]+=x*w2v; acc[3][ow]+=x*w3;
                    }
                }
            }
        }
    }
    __shared__ float red[4*1540];
    #pragma unroll
    for (int q=0;q<4;q++)
        #pragma unroll
        for (int ow=0;ow<6;ow++) red[wave*1540 + lane*24 + q*6 + ow] = acc[q][ow];
    __syncthreads();
    float* rb = raw2 + (size_t)ciq*92160;
    for (int idx = threadIdx.x; idx < 1536; idx += 256){
        int lane2 = idx/24, j = idx%24;
        float s = red[0*1540 + lane2*24 + j] + red[1*1540 + lane2*24 + j]
                + red[2*1540 + lane2*24 + j] + red[3*1540 + lane2*24 + j];
        int q = j/6, ow = j%6;
        int co = q*64 + lane2;
        rb[(((size_t)(b*256+co)*5 + od)*6 + oh)*6 + ow] = s;
    }
}

// conv2 BN stats from raw interior (16 buffers) + analytic background class counts
__global__ __launch_bounds__(64) void k_stats_c2(const float* __restrict__ raw2, const float* __restrict__ bgraw2,
                                                 const float* __restrict__ cb2, const float* __restrict__ cg2,
                                                 const float* __restrict__ cbe2, float* __restrict__ ACb2){
    int o = blockIdx.x;
    int lane = threadIdx.x;
    float s=0.f, ss=0.f;
    for (int idx=lane; idx<360; idx+=64){
        int b = idx/180; int p = idx%180;
        int d = p/36; int rem = p%36; int h = rem/6; int w = rem%6;
        size_t base = (((size_t)(b*256+o)*5 + d)*6 + h)*6 + w;
        float v = 0.f;
        #pragma unroll
        for (int q=0;q<16;q++) v += raw2[q*92160+base];
        s += v; ss += v*v;
    }
    #pragma unroll
    for (int off=32; off>0; off>>=1){ s += __shfl_down(s,off); ss += __shfl_down(ss,off); }
    if (lane==0){
        const int n2[8] = {3744,104,104,0,936,26,26,0};   // per batch; x2 batches
        float bgv[8];
        #pragma unroll
        for (int c=0;c<8;c++){ bgv[c]=bgraw2[o*8+c]; s += 2.f*n2[c]*bgv[c]; ss += 2.f*n2[c]*bgv[c]*bgv[c]; }
        const float N = 10240.f;
        float b = cb2[o];
        float sum_y = s + N*b;
        float ssq_y = ss + 2.f*b*s + N*b*b;
        float m = sum_y/N;
        float var = ssq_y/N - m*m;
        float A = cg2[o]*rsqrtf(var+EPS); float C = cbe2[o] - m*A;
        ACb2[o]=A; ACb2[256+o]=C;
        for (int c=0;c<8;c++) ACb2[512+o*8+c] = fmaxf((bgv[c]+b)*A + C, 0.f);
    }
}

// I2p[b][ci][7][9][12]
__global__ void k_fill_I2(const float* __restrict__ raw2, const float* __restrict__ ACb2,
                          const float* __restrict__ cb2, float* __restrict__ I2p){
    int i = blockIdx.x*blockDim.x + threadIdx.x;   // grid exactly 387,072
    int wpad = i % 12; int r = i / 12;
    int hpad = r % 9; r /= 9;
    int dpad = r % 7; r /= 7;
    int ci = r % 256; int b = r / 256;
    float val;
    if (dpad==0 || dpad==6 || hpad==0 || wpad==0 || wpad>8) val = 0.f;
    else {
        int d = dpad-1, h = hpad-1, w = wpad-1;
        if (h<6 && w<6){
            size_t idx = (((size_t)(b*256+ci)*5 + d)*6 + h)*6 + w;
            float raw = 0.f;
            #pragma unroll
            for (int q=0;q<16;q++) raw += raw2[q*92160+idx];
            val = fmaxf((raw + cb2[ci])*ACb2[ci] + ACb2[256+ci], 0.f);
        } else {
            int cls = ((d==0)?4:0) | ((h==0)?2:0) | ((w==0)?1:0);
            val = ACb2[512 + ci*8 + cls];
        }
    }
    I2p[i] = val;
}

// conv3 background classes: bgraw3[o][12]; coalesced via wT3
__global__ __launch_bounds__(256) void k_bg3(const float* __restrict__ wT3, const float* __restrict__ ACb2,
                                             float* __restrict__ bgraw3){
    int o = threadIdx.x;
    int ci0 = blockIdx.x*8;
    float acc[12];
    #pragma unroll
    for (int c=0;c<12;c++) acc[c]=0.f;
    for (int ci=ci0; ci<ci0+8; ci++){
        float w[27];
        const float* wp = wT3 + (size_t)ci*27*256 + o;
        #pragma unroll
        for (int t=0;t<27;t++) w[t] = wp[t*256];
        const float* bg = ACb2 + 512 + ci*8;
        float bgv[8];
        #pragma unroll
        for (int q=0;q<8;q++) bgv[q]=bg[q];
        #pragma unroll
        for (int c=0;c<12;c++){
            const int odc = c>>2; const int h0 = (c>>1)&1; const int w0 = c&1;
            float sum = 0.f;
            #pragma unroll
            for (int kd=0;kd<3;kd++){
                const int d = 2*odc-1+kd; if (d<0||d>=5) continue;
                const int db = (d==0)?4:0;
                #pragma unroll
                for (int kh=0;kh<3;kh++){
                    if (h0 && kh==0) continue;
                    const int hb = (h0 && kh==1)?2:0;
                    #pragma unroll
                    for (int kw=0;kw<3;kw++){
                        if (w0 && kw==0) continue;
                        const int wb = (w0 && kw==1)?1:0;
                        sum += bgv[db|hb|wb]*w[(kd*3+kh)*3+kw];
                    }
                }
            }
            acc[c] += sum;
        }
    }
    #pragma unroll
    for (int c=0;c<12;c++) atomicAdd(&bgraw3[o*12+c], acc[c]);
}

// conv3: grid 768 = ((b*3+od)*4+oh)*32+ciq ; 256 thr = 4 waves x 2 ci; LDS reduce -> store buf[ciq]
__global__ __launch_bounds__(256) void k_conv3(const float* __restrict__ I2p, const float* __restrict__ wT3,
                                               float* __restrict__ raw3){
    int blk = blockIdx.x;
    int ciq = blk & 31; blk >>= 5;
    int oh = blk % 4; blk /= 4;
    int od = blk % 3; int b = blk / 3;
    int wave = threadIdx.x >> 6, lane = threadIdx.x & 63;
    float acc[4][4];
    #pragma unroll
    for (int q=0;q<4;q++)
        #pragma unroll
        for (int i=0;i<4;i++) acc[q][i]=0.f;
    int ci0 = ciq*8 + wave*2;
    for (int ci = ci0; ci < ci0+2; ci++){
        const float* base = I2p + ((size_t)(b*256+ci)*7 + 2*od)*108 + (2*oh)*12;
        const float* wp0 = wT3 + (size_t)ci*27*256 + lane;
        #pragma unroll
        for (int kd=0;kd<3;kd++){
            #pragma unroll
            for (int kh=0;kh<3;kh++){
                float row[12];
                const float4* rp = (const float4*)(base + kd*108 + kh*12);
                #pragma unroll
                for (int i=0;i<3;i++){ float4 t=rp[i]; row[4*i]=t.x; row[4*i+1]=t.y; row[4*i+2]=t.z; row[4*i+3]=t.w; }
                const float* wp = wp0 + (kd*3+kh)*3*256;
                #pragma unroll
                for (int kw=0;kw<3;kw++){
                    float w0=wp[kw*256], w1=wp[kw*256+64], w2v=wp[kw*256+128], w3=wp[kw*256+192];
                    #pragma unroll
                    for (int ow=0;ow<4;ow++){
                        float x = row[2*ow+kw];
                        acc[0][ow]+=x*w0; acc[1][ow]+=x*w1; acc[2][ow]+=x*w2v; acc[3][ow]+=x*w3;
                    }
                }
            }
        }
    }
    __shared__ float red[4*1028];
    #pragma unroll
    for (int q=0;q<4;q++)
        #pragma unroll
        for (int ow=0;ow<4;ow++) red[wave*1028 + lane*16 + q*4 + ow] = acc[q][ow];
    __syncthreads();
    float* rb = raw3 + (size_t)ciq*24576;
    for (int idx = threadIdx.x; idx < 1024; idx += 256){
        int lane2 = idx/16, j = idx%16;
        float s = red[0*1028 + lane2*16 + j] + red[1*1028 + lane2*16 + j]
                + red[2*1028 + lane2*16 + j] + red[3*1028 + lane2*16 + j];
        int q = j/4, ow = j%4;
        int co = q*64 + lane2;
        rb[(((size_t)(b*256+co)*3 + od)*4 + oh)*4 + ow] = s;
    }
}

// conv3 BN stats from raw interior (32 buffers) + analytic class counts
__global__ __launch_bounds__(64) void k_stats_c3(const float* __restrict__ raw3, const float* __restrict__ bgraw3,
                                                 const float* __restrict__ cb3, const float* __restrict__ cg3,
                                                 const float* __restrict__ cbe3, float* __restrict__ AC3){
    int o = blockIdx.x;
    int lane = threadIdx.x;
    float s=0.f, ss=0.f;
    for (int idx=lane; idx<96; idx+=64){
        int b = idx/48; int p = idx%48;
        int d = p/16; int rem = p%16; int h = rem/4; int w = rem%4;
        size_t base = (((size_t)(b*256+o)*3 + d)*4 + h)*4 + w;
        float v = 0.f;
        #pragma unroll
        for (int q=0;q<32;q++) v += raw3[q*24576+base];
        s += v; ss += v*v;
    }
    #pragma unroll
    for (int off=32; off>0; off>>=1){ s += __shfl_down(s,off); ss += __shfl_down(ss,off); }
    if (lane==0){
        const int n3hw[4] = {216,12,12,0};   // per (b,od)
        for (int c=0;c<12;c++){
            float bg = bgraw3[o*12+c];
            float n = 2.f*n3hw[c&3];
            s += n*bg; ss += n*bg*bg;
        }
        const float N = 1536.f;
        float b = cb3[o];
        float sum_y = s + N*b;
        float ssq_y = ss + 2.f*b*s + N*b*b;
        float m = sum_y/N;
        float var = ssq_y/N - m*m;
        float A = cg3[o]*rsqrtf(var+EPS);
        AC3[o]=A; AC3[256+o]=cbe3[o] - m*A;
    }
}

// final output directly from raw3/bg3
__global__ void k_final(const float* __restrict__ raw3, const float* __restrict__ bgraw3,
                        const float* __restrict__ cb3, const float* __restrict__ AC3,
                        float* __restrict__ out){
    int i = blockIdx.x*blockDim.x + threadIdx.x;
    if (i >= 2*256*3*16*16) return;
    int ow = i % 16; int r = i / 16;
    int oh = r % 16; r /= 16;
    int od = r % 3; r /= 3;
    int o = r % 256; int b = r / 256;
    float v;
    if (oh<4 && ow<4){
        size_t base = (((size_t)(b*256+o)*3 + od)*4 + oh)*4 + ow;
        v = 0.f;
        #pragma unroll
        for (int q=0;q<32;q++) v += raw3[q*24576+base];
    } else {
        v = bgraw3[o*12 + od*4 + ((oh==0)?2:0) + ((ow==0)?1:0)];
    }
    out[i] = fmaxf((v + cb3[o])*AC3[o] + AC3[256+o], 0.f);
}

// ================= launch =================

extern "C" void kernel_launch(void* const* d_in, const int* in_sizes, int n_in,
                              void* d_out, int out_size, void* d_ws, size_t ws_size,
                              hipStream_t stream) {
    const float* vf    = (const float*)d_in[0];
    const int*   coords= (const int*)d_in[1];
    const float* w1    = (const float*)d_in[5];
    const float* b1    = (const float*)d_in[6];
    const float* g1    = (const float*)d_in[7];
    const float* be1   = (const float*)d_in[8];
    const float* w2    = (const float*)d_in[9];
    const float* b2    = (const float*)d_in[10];
    const float* g2    = (const float*)d_in[11];
    const float* be2   = (const float*)d_in[12];
    const float* cw1   = (const float*)d_in[13];
    const float* cb1   = (const float*)d_in[14];
    const float* cg1   = (const float*)d_in[15];
    const float* cbe1  = (const float*)d_in[16];
    const float* cw2   = (const float*)d_in[17];
    const float* cb2   = (const float*)d_in[18];
    const float* cg2   = (const float*)d_in[19];
    const float* cbe2  = (const float*)d_in[20];
    const float* cw3   = (const float*)d_in[21];
    const float* cb3   = (const float*)d_in[22];
    const float* cg3   = (const float*)d_in[23];
    const float* cbe3  = (const float*)d_in[24];
    float* out = (float*)d_out;
    float* ws  = (float*)d_ws;
    __hip_bfloat16* I0cl = (__hip_bfloat16*)(ws + OFF_I0CL);
    __hip_bfloat16* wT1b = (__hip_bfloat16*)(ws + OFF_WT1B);

    hipMemsetAsync(ws + OFF_SX,  0,    4192*4, stream);        // SX + MST
    hipMemsetAsync(ws + OFF_BG2, 0,    5120*4, stream);        // BG2 + BG3
    hipMemsetAsync(ws + OFF_WIN, 0xFF, 16000*4, stream);
    hipMemsetAsync(ws + OFF_I0CL, 0, 1485824ull*4, stream);    // bf16 I0cl (incl slack)

    k_t_tile<<<777,256,0,stream>>>(cw2, cw3, w2, cw1, ws+OFF_WT2, ws+OFF_WT3, ws+OFF_W2T, wT1b);
    k_stats_x<<<768,256,0,stream>>>(vf, ws+OFF_SX);
    k_ac1<<<1,64,0,stream>>>(ws+OFF_SX, w1,b1,g1,be1, ws+OFF_AC1);
    k_vfe1<<<6000,256,0,stream>>>(vf, w1, ws+OFF_AC1, ws+OFF_F1);
    k_stats_f1<<<512,256,0,stream>>>(ws+OFF_F1, ws+OFF_MST);
    k_ac2<<<128,64,0,stream>>>(ws+OFF_MST, w2,b2,g2,be2, ws+OFF_AC2);
    k_scatter<<<94,256,0,stream>>>(coords, (int*)(ws+OFF_WIN));
    k_I0<<<800,256,0,stream>>>((int*)(ws+OFF_WIN), ws+OFF_F1, ws+OFF_W2T, ws+OFF_AC2, I0cl);
    k_conv1m<<<1760,256,0,stream>>>(I0cl, wT1b, ws+OFF_RAW1);
    k_stats_c1<<<128,256,0,stream>>>(ws+OFF_RAW1, cb1,cg1,cbe1, ws+OFF_ACB1);
    k_fill_I1<<<2288,256,0,stream>>>(ws+OFF_RAW1, ws+OFF_ACB1, cb1, ws+OFF_I1);
    k_bg2<<<16,256,0,stream>>>(ws+OFF_WT2, ws+OFF_ACB1, ws+OFF_BG2);
    k_conv2<<<960,256,0,stream>>>(ws+OFF_I1, ws+OFF_WT2, ws+OFF_RAW2);
    k_stats_c2<<<256,64,0,stream>>>(ws+OFF_RAW2, ws+OFF_BG2, cb2, cg2, cbe2, ws+OFF_ACB2);
    k_fill_I2<<<1512,256,0,stream>>>(ws+OFF_RAW2, ws+OFF_ACB2, cb2, ws+OFF_I2);
    k_bg3<<<32,256,0,stream>>>(ws+OFF_WT3, ws+OFF_ACB2, ws+OFF_BG3);
    k_conv3<<<768,256,0,stream>>>(ws+OFF_I2, ws+OFF_WT3, ws+OFF_RAW3);
    k_stats_c3<<<256,64,0,stream>>>(ws+OFF_RAW3, ws+OFF_BG3, cb3, cg3, cbe3, ws+OFF_AC3);
    k_final<<<1536,256,0,stream>>>(ws+OFF_RAW3, ws+OFF_BG3, cb3, ws+OFF_AC3, out);
}

// Round 10
// 388.066 us; speedup vs baseline: 1.1240x; 1.1240x over previous
//
#include <hip/hip_runtime.h>
#include <hip/hip_bf16.h>

#define EPS 1e-5f

// ---- problem dims ----
#define BB 2
#define NV 12000
#define NP 32
#define CIN 5
#define GD 20
// conv1: active out 10x11x11; conv2 region 5x6x6; conv3 region 3x4x4

typedef __attribute__((ext_vector_type(8))) short bf16x8;
typedef __attribute__((ext_vector_type(4))) float f32x4;

// ---- workspace layout (float offsets) ----
static const size_t OFF_SX   = 0;         // 32
static const size_t OFF_MST  = 32;        // 4160   [memset0: 0..4192]
static const size_t OFF_AC1  = 4192;      // 128
static const size_t OFF_AC2  = 4320;      // 256
static const size_t OFF_ACB1 = 4576;      // 384  (A[128],C[128],bg1[128])
static const size_t OFF_ACB2 = 4960;      // 2560 (A[256],C[256],bgn2[256*8])
static const size_t OFF_AC3  = 7520;      // 512
static const size_t OFF_BG2  = 8032;      // 2048   [memset1: 8032..13152]
static const size_t OFF_BG3  = 10080;     // 3072
static const size_t OFF_W2T  = 13152;     // 8192
static const size_t OFF_WIN  = 21344;     // 16000 ints [memset 0xFF]
static const size_t OFF_F1   = 37344;     // 1,536,000
static const size_t OFF_I0CL = 1573344;   // bf16 [b][21][23][24][128ci] (+slack) = 1,485,824 floats (memset 0)
static const size_t OFF_I1   = 3059168;   // 585,728   [b][ci][11][13][16]
static const size_t OFF_I2   = 3644896;   // 387,072   [b][ci][7][9][12]
static const size_t OFF_WT1B = 4031968;   // bf16 [27][128co][128ci] = 221,184 floats
static const size_t OFF_WT2  = 4253152;   // 884,736
static const size_t OFF_WT3  = 5137888;   // 1,769,472
static const size_t OFF_RAW1 = 6907360;   // 4 x 309,760
static const size_t OFF_RAW2 = 8146400;   // 16 x 92,160
static const size_t OFF_RAW3 = 9620960;   // 32 x 24,576
static const size_t OFF_MSTP = 10407392;  // 256 x 4160 partials (no memset needed; fully written)
// end = 11,472,352 floats = 45.9 MB

// ================= VFE stage =================

// vectorized: one thread per 4-point group (5 float4 loads = 80B contiguous)
__global__ __launch_bounds__(256) void k_stats_x(const float* __restrict__ vf, float* __restrict__ out) {
    float ls[5] = {0,0,0,0,0};
    float lq[15];
    #pragma unroll
    for (int i=0;i<15;i++) lq[i]=0.f;
    const int ng = (BB*NV*NP)/4;   // 192,000 groups
    for (int g = blockIdx.x*blockDim.x + threadIdx.x; g < ng; g += gridDim.x*blockDim.x) {
        float xx[20];
        const float4* x4 = (const float4*)(vf + (size_t)g*20);
        #pragma unroll
        for (int i=0;i<5;i++){ float4 t = x4[i]; xx[4*i]=t.x; xx[4*i+1]=t.y; xx[4*i+2]=t.z; xx[4*i+3]=t.w; }
        #pragma unroll
        for (int p=0;p<4;p++){
            const float* v = xx + p*5;
            int k=0;
            #pragma unroll
            for (int c=0;c<5;c++){
                ls[c]+=v[c];
                #pragma unroll
                for(int c2=c;c2<5;c2++){ lq[k++]+=v[c]*v[c2]; }
            }
        }
    }
    __shared__ float sh[20];
    if (threadIdx.x < 20) sh[threadIdx.x]=0.f;
    __syncthreads();
    #pragma unroll
    for (int c=0;c<5;c++) atomicAdd(&sh[c], ls[c]);
    #pragma unroll
    for (int k=0;k<15;k++) atomicAdd(&sh[5+k], lq[k]);
    __syncthreads();
    if (threadIdx.x<20) atomicAdd(&out[threadIdx.x], sh[threadIdx.x]);
}

__global__ void k_ac1(const float* __restrict__ stats, const float* __restrict__ w1,
                      const float* __restrict__ b1, const float* __restrict__ g1,
                      const float* __restrict__ be1, float* __restrict__ AC1){
    int o = threadIdx.x; if (o>=64) return;
    const float N = (float)(BB*NV*NP);
    float w[5];
    #pragma unroll
    for(int c=0;c<5;c++) w[c]=w1[o*5+c];
    float b=b1[o];
    float wd=0;
    #pragma unroll
    for(int c=0;c<5;c++) wd += w[c]*stats[c];
    float m = wd/N + b;
    float q=0; int kk=5;
    for(int c=0;c<5;c++) for(int c2=c;c2<5;c2++){ float s=stats[kk++]; q += (c==c2?1.f:2.f)*w[c]*w[c2]*s; }
    q = q/N + 2.f*b*wd/N + b*b;
    float var = q - m*m;
    float A = g1[o]*rsqrtf(var + EPS);
    AC1[o] = A;
    AC1[64+o] = be1[o] + (b - m)*A;
}

__global__ __launch_bounds__(256) void k_vfe1(const float* __restrict__ vf, const float* __restrict__ w1,
                                              const float* __restrict__ AC1, float* __restrict__ f1){
    int wave = threadIdx.x >> 6;
    int lane = threadIdx.x & 63;
    int v = blockIdx.x*4 + wave;
    if (v >= BB*NV) return;
    float w[5];
    #pragma unroll
    for (int c=0;c<5;c++) w[c] = w1[lane*5+c];
    float A = AC1[lane], Cc = AC1[64+lane];
    const float* x = vf + (size_t)v*(NP*CIN);
    float mx = -1e30f;
    #pragma unroll
    for (int pc = 0; pc < 8; pc++) {
        float xx[20];
        const float4* x4 = (const float4*)(x + pc*20);
        #pragma unroll
        for (int i=0;i<5;i++){ float4 t = x4[i]; xx[4*i]=t.x; xx[4*i+1]=t.y; xx[4*i+2]=t.z; xx[4*i+3]=t.w; }
        #pragma unroll
        for (int j=0;j<4;j++){
            float y = xx[j*5]*w[0]+xx[j*5+1]*w[1]+xx[j*5+2]*w[2]+xx[j*5+3]*w[3]+xx[j*5+4]*w[4];
            mx = fmaxf(mx, y*A + Cc);
        }
    }
    f1[(size_t)v*64 + lane] = fmaxf(mx, 0.f);
}

// atomic-free: each block writes its 4160-float accumulator to a private partial slice
__global__ __launch_bounds__(256) void k_stats_f1(const float* __restrict__ f1, float* __restrict__ Mpart){
    __shared__ float tile[16][64];
    __shared__ float ssum[64];
    int t = threadIdx.x;
    if (t < 64) ssum[t]=0.f;
    float acc[4][4];
    #pragma unroll
    for(int i=0;i<4;i++)
        #pragma unroll
        for(int j=0;j<4;j++) acc[i][j]=0.f;
    int i4 = (t>>4)*4, j4 = (t&15)*4;
    const int NT = (BB*NV)/16; // 1500
    for (int tl = blockIdx.x; tl < NT; tl += gridDim.x) {
        __syncthreads();
        for (int i = t; i < 16*64; i += 256) tile[i>>6][i&63] = f1[(size_t)tl*1024 + i];
        __syncthreads();
        #pragma unroll
        for (int r=0;r<16;r++){
            float a[4], bb[4];
            #pragma unroll
            for (int u=0;u<4;u++) a[u]=tile[r][i4+u];
            #pragma unroll
            for (int u=0;u<4;u++) bb[u]=tile[r][j4+u];
            #pragma unroll
            for (int u=0;u<4;u++)
                #pragma unroll
                for (int q=0;q<4;q++) acc[u][q] += a[u]*bb[q];
        }
        if (t < 64) {
            float s=0;
            #pragma unroll
            for(int r=0;r<16;r++) s+=tile[r][t];
            ssum[t]+=s;
        }
    }
    float* mp = Mpart + (size_t)blockIdx.x*4160;
    #pragma unroll
    for(int i=0;i<4;i++)
        #pragma unroll
        for(int j=0;j<4;j++) mp[(size_t)(i4+i)*64 + (j4+j)] = acc[i][j];
    __syncthreads();
    if (t<64) mp[4096 + t] = ssum[t];
}

// reduce 256 partial slices -> Mst[4160]
__global__ __launch_bounds__(64) void k_red_mst(const float* __restrict__ Mpart, float* __restrict__ Mst){
    int e = blockIdx.x*64 + threadIdx.x;
    if (e >= 4160) return;
    float s = 0.f;
    #pragma unroll 8
    for (int p=0;p<256;p++) s += Mpart[(size_t)p*4160 + e];
    Mst[e] = s;
}

// parallel ac2: one block per o (128 blocks x 64 lanes)
__global__ __launch_bounds__(64) void k_ac2(const float* __restrict__ Mst, const float* __restrict__ w2,
                                            const float* __restrict__ b2, const float* __restrict__ g2,
                                            const float* __restrict__ be2, float* __restrict__ AC2){
    int o = blockIdx.x;
    int j = threadIdx.x;
    const float N = (float)(BB*NV);
    const float* M = Mst; const float* sv = Mst+4096;
    const float* wrow = w2 + o*64;
    float wj = wrow[j];
    float sj = 0.f;
    #pragma unroll 8
    for (int c=0;c<64;c++) sj += wrow[c]*M[c*64+j];
    float q = wj*sj;
    float wdp = wj*sv[j];
    #pragma unroll
    for (int off=32; off>0; off>>=1){ q += __shfl_down(q,off); wdp += __shfl_down(wdp,off); }
    if (j==0){
        float b = b2[o];
        float m = wdp/N + b;
        float qq = q/N + 2.f*b*wdp/N + b*b;
        float var = qq - m*m;
        float A = g2[o]*rsqrtf(var+EPS);
        AC2[o]=A; AC2[128+o]= be2[o] + (b-m)*A;
    }
}

// ================= scatter =================

__global__ void k_scatter(const int* __restrict__ coords, int* __restrict__ winner){
    int i = blockIdx.x*blockDim.x+threadIdx.x;
    if (i >= BB*NV) return;
    int b = i / NV, n = i % NV;
    int d = coords[(size_t)i*3], h = coords[(size_t)i*3+1], w = coords[(size_t)i*3+2];
    if (d<0||d>=GD||h<0||h>=GD||w<0||w>=GD) return;
    atomicMax(&winner[b*8000 + d*400 + h*20 + w], n);
}

// FUSED vfe2 + scatter-fill into channels-last bf16 I0cl[b][21][23][24][128].
__global__ __launch_bounds__(256) void k_I0(const int* __restrict__ winner, const float* __restrict__ f1,
                                            const float* __restrict__ w2T, const float* __restrict__ AC2,
                                            __hip_bfloat16* __restrict__ I0cl){
    int blk = blockIdx.x;
    int b = blk / 400; int dh = blk % 400;
    int d = dh / 20, h = dh % 20;
    __shared__ int win[20];
    __shared__ float f1sh[20][64];
    __shared__ float sh[20*128];   // [w][ci]
    int t = threadIdx.x;
    if (t < 20) win[t] = winner[b*8000 + dh*20 + t];
    __syncthreads();
    for (int idx = t; idx < 1280; idx += 256){
        int cell = idx >> 6, c = idx & 63;
        int n = win[cell];
        f1sh[cell][c] = (n>=0) ? f1[((size_t)(b*NV+n))*64 + c] : 0.f;
    }
    __syncthreads();
    int o = t & 127;
    int half = t >> 7;
    float A = AC2[o], C = AC2[128+o];
    for (int p=0;p<10;p++){
        int cell = p*2 + half;
        float acc = 0.f;
        if (win[cell] >= 0){
            #pragma unroll
            for (int c=0;c<64;c++) acc += f1sh[cell][c]*w2T[c*128+o];
            acc = fmaxf(acc*A + C, 0.f);
        }
        sh[cell*128 + o] = acc;
    }
    __syncthreads();
    __hip_bfloat16* outp = I0cl + (((size_t)(b*21 + d+1)*23 + h+1)*24 + 1)*128;
    for (int idx = t; idx < 2560; idx += 256) outp[idx] = __float2bfloat16(sh[idx]);
}

// ================= merged weight prep =================
// blocks 0..215: wT2 tiles; 216..647: wT3 tiles; 648: w2T; 649..776: wT1b (bf16 pack, co = blk-649)
__global__ __launch_bounds__(256) void k_t_tile(const float* __restrict__ cw2, const float* __restrict__ cw3,
                                                const float* __restrict__ w2, const float* __restrict__ cw1,
                                                float* __restrict__ wT2, float* __restrict__ wT3,
                                                float* __restrict__ w2T, __hip_bfloat16* __restrict__ wT1b){
    int blk = blockIdx.x;
    if (blk >= 649){
        int co = blk - 649;
        __shared__ float tlw[3456];
        int t = threadIdx.x;
        for (int j=t; j<3456; j+=256) tlw[j] = cw1[(size_t)co*3456 + j];   // j = ci*27+tap
        __syncthreads();
        for (int idx=t; idx<3456; idx+=256){
            int tap = idx >> 7, ci = idx & 127;
            wT1b[((size_t)(tap*128 + co) << 7) + ci] = __float2bfloat16(tlw[ci*27 + tap]);
        }
        return;
    }
    if (blk == 648){
        for (int i=threadIdx.x; i<8192; i+=256){ int o=i>>6, c=i&63; w2T[c*128+o]=w2[i]; }
        return;
    }
    const float* src; float* dst; int CO, R;
    if (blk < 216){ src=cw2; dst=wT2; CO=256; R=3456; }
    else { blk-=216; src=cw3; dst=wT3; CO=256; R=6912; }
    int nrt = R/64;
    int rt = blk % nrt, ct = blk / nrt;
    int r0 = rt*64, c0 = ct*64;
    __shared__ float tl[64][65];
    int tj = threadIdx.x & 63;
    int ti0 = threadIdx.x >> 6;
    #pragma unroll
    for (int k=0;k<16;k++){
        int i = ti0 + k*4;
        tl[i][tj] = src[(size_t)(c0+i)*R + r0 + tj];
    }
    __syncthreads();
    #pragma unroll
    for (int k=0;k<16;k++){
        int j = ti0 + k*4;
        dst[(size_t)(r0+j)*CO + c0 + tj] = tl[tj][j];
    }
}

// ================= conv1 via MFMA (bf16 implicit GEMM) =================
// grid 1760 = ((b*10+od)*11+oh)*8 + coq ; 4 waves = kq (K-slices of 32 ci); each wave 27 MFMA.
__global__ __launch_bounds__(256) void k_conv1m(const __hip_bfloat16* __restrict__ I0cl,
                                                const __hip_bfloat16* __restrict__ wT1b,
                                                float* __restrict__ raw1){
    int blk = blockIdx.x;
    int coq = blk & 7; blk >>= 3;
    int oh = blk % 11; blk /= 11;
    int od = blk % 10; int b = blk / 10;
    int kq = threadIdx.x >> 6, lane = threadIdx.x & 63;
    int col = lane & 15, quad = lane >> 4;
    int co0 = coq*16;
    int ci_base = kq*32 + quad*8;
    f32x4 acc = {0.f,0.f,0.f,0.f};
    const __hip_bfloat16* Bb = I0cl + (size_t)b*21*23*24*128 + (2*col)*128 + ci_base;
    const __hip_bfloat16* Ab = wT1b + (size_t)(co0 + col)*128 + ci_base;
    #pragma unroll 3
    for (int tap=0; tap<27; tap++){
        int kd = tap/9, kh = (tap/3)%3, kw = tap%3;
        int d = 2*od + kd, h = 2*oh + kh;     // padded indices
        const __hip_bfloat16* bp = Bb + ((size_t)(d*23 + h)*24 + kw)*128;
        const __hip_bfloat16* ap = Ab + (size_t)tap*16384;
        bf16x8 a0 = *(const bf16x8*)ap;
        bf16x8 b0 = *(const bf16x8*)bp;
        acc = __builtin_amdgcn_mfma_f32_16x16x32_bf16(a0, b0, acc, 0, 0, 0);
    }
    if (col < 11){
        #pragma unroll
        for (int r=0;r<4;r++){
            int co = co0 + quad*4 + r;
            raw1[(size_t)kq*309760 + (((size_t)(b*128+co)*10 + od)*11 + oh)*11 + col] = acc[r];
        }
    }
}

// stats for conv1 (zero background), sums 4 K-split buffers
__global__ __launch_bounds__(256) void k_stats_c1(const float* __restrict__ raw1, const float* __restrict__ cb,
                                                  const float* __restrict__ cg, const float* __restrict__ cbe,
                                                  float* __restrict__ ACb1){
    int co = blockIdx.x;
    float s=0, ss=0;
    for (int b=0;b<2;b++){
        size_t base = ((size_t)(b*128+co))*1210;
        for (int i=threadIdx.x; i<1210; i+=256){
            float v = raw1[base+i] + raw1[309760+base+i] + raw1[2*309760+base+i] + raw1[3*309760+base+i];
            s+=v; ss+=v*v;
        }
    }
    __shared__ float sh1[256], sh2[256];
    sh1[threadIdx.x]=s; sh2[threadIdx.x]=ss; __syncthreads();
    for (int st=128; st>0; st>>=1){
        if (threadIdx.x<st){ sh1[threadIdx.x]+=sh1[threadIdx.x+st]; sh2[threadIdx.x]+=sh2[threadIdx.x+st]; }
        __syncthreads();
    }
    if (threadIdx.x==0){
        float bias = cb[co];
        const float N = 81920.f;   // 2*10*64*64
        float sum_y = sh1[0] + N*bias;
        float ssq_y = sh2[0] + 2.f*bias*sh1[0] + N*bias*bias;
        float m = sum_y/N;
        float var = ssq_y/N - m*m;
        float A = cg[co]*rsqrtf(var+EPS);
        float C = cbe[co] - m*A;
        ACb1[co]=A; ACb1[128+co]=C;
        ACb1[256+co]=fmaxf(bias*A + C, 0.f);  // bg1
    }
}

// I1p[b][ci][11][13][16]
__global__ void k_fill_I1(const float* __restrict__ raw1, const float* __restrict__ ACb1,
                          const float* __restrict__ cb, float* __restrict__ I1p){
    int i = blockIdx.x*blockDim.x + threadIdx.x;   // grid exactly 585,728
    int wpad = i % 16; int r = i / 16;
    int hpad = r % 13; r /= 13;
    int dpad = r % 11; r /= 11;
    int ci = r % 128; int b = r / 128;
    float val;
    if (dpad==0 || hpad==0 || wpad==0 || wpad>12) val = 0.f;
    else {
        int d = dpad-1, h = hpad-1, w = wpad-1;
        if (h < 11 && w < 11){
            size_t idx = (((size_t)(b*128+ci)*10 + d)*11 + h)*11 + w;
            float raw = raw1[idx] + raw1[309760+idx] + raw1[2*309760+idx] + raw1[3*309760+idx];
            val = fmaxf((raw + cb[ci])*ACb1[ci] + ACb1[128+ci], 0.f);
        } else val = ACb1[256+ci];
    }
    I1p[i] = val;
}

// conv2 background class constants: bgraw2[o][8]; coalesced via wT2
__global__ __launch_bounds__(256) void k_bg2(const float* __restrict__ wT2, const float* __restrict__ ACb1,
                                             float* __restrict__ bgraw2){
    int o = threadIdx.x;
    int ci0 = blockIdx.x*8;
    float acc[8];
    #pragma unroll
    for (int c=0;c<8;c++) acc[c]=0.f;
    for (int ci=ci0; ci<ci0+8; ci++){
        float w[27];
        const float* wp = wT2 + (size_t)ci*27*256 + o;
        #pragma unroll
        for (int t=0;t<27;t++) w[t] = wp[t*256];
        float bg = ACb1[256+ci];
        float sw0[9], sw1[9];
        #pragma unroll
        for (int t9=0;t9<9;t9++){ sw1[t9]=w[3*t9+1]+w[3*t9+2]; sw0[t9]=w[3*t9]+sw1[t9]; }
        #pragma unroll
        for (int cls=0; cls<8; cls++){
            const int d0=(cls>>2)&1, h0=(cls>>1)&1, w0=cls&1;
            float ws=0.f;
            #pragma unroll
            for (int kd=0;kd<3;kd++){
                if (d0 && kd==0) continue;
                #pragma unroll
                for (int kh=0;kh<3;kh++){
                    if (h0 && kh==0) continue;
                    ws += w0 ? sw1[kd*3+kh] : sw0[kd*3+kh];
                }
            }
            acc[cls] += bg*ws;
        }
    }
    #pragma unroll
    for (int cls=0;cls<8;cls++) atomicAdd(&bgraw2[o*8+cls], acc[cls]);
}

// conv2: grid 960 = ((b*5+od)*6+oh)*16+ciq ; 256 thr = 4 waves x 2 ci; LDS reduce -> store buf[ciq]
__global__ __launch_bounds__(256) void k_conv2(const float* __restrict__ I1p, const float* __restrict__ wT2,
                                               float* __restrict__ raw2){
    int blk = blockIdx.x;
    int ciq = blk & 15; blk >>= 4;
    int oh = blk % 6; blk /= 6;
    int od = blk % 5; int b = blk / 5;
    int wave = threadIdx.x >> 6, lane = threadIdx.x & 63;
    float acc[4][6];
    #pragma unroll
    for (int q=0;q<4;q++)
        #pragma unroll
        for (int i=0;i<6;i++) acc[q][i]=0.f;
    int ci0 = ciq*8 + wave*2;
    for (int ci = ci0; ci < ci0+2; ci++){
        const float* base = I1p + ((size_t)(b*128+ci)*11 + 2*od)*208 + (2*oh)*16;
        const float* wp0 = wT2 + (size_t)ci*27*256 + lane;
        #pragma unroll
        for (int kd=0;kd<3;kd++){
            #pragma unroll
            for (int kh=0;kh<3;kh++){
                float row[16];
                const float4* rp = (const float4*)(base + kd*208 + kh*16);
                #pragma unroll
                for (int i=0;i<4;i++){ float4 t=rp[i]; row[4*i]=t.x; row[4*i+1]=t.y; row[4*i+2]=t.z; row[4*i+3]=t.w; }
                const float* wp = wp0 + (kd*3+kh)*3*256;
                #pragma unroll
                for (int kw=0;kw<3;kw++){
                    float w0=wp[kw*256], w1=wp[kw*256+64], w2v=wp[kw*256+128], w3=wp[kw*256+192];
                    #pragma unroll
                    for (int ow=0;ow<6;ow++){
                        float x = row[2*ow+kw];
                        acc[0][ow]+=x*w0; acc[1][ow]+=x*w1; acc[2][ow]+=x*w2v; acc[3][ow]+=x*w3;
                    }
                }
            }
        }
    }
    __shared__ float red[4*1540];
    #pragma unroll
    for (int q=0;q<4;q++)
        #pragma unroll
        for (int ow=0;ow<6;ow++) red[wave*1540 + lane*24 + q*6 + ow] = acc[q][ow];
    __syncthreads();
    float* rb = raw2 + (size_t)ciq*92160;
    for (int idx = threadIdx.x; idx < 1536; idx += 256){
        int lane2 = idx/24, j = idx%24;
        float s = red[0*1540 + lane2*24 + j] + red[1*1540 + lane2*24 + j]
                + red[2*1540 + lane2*24 + j] + red[3*1540 + lane2*24 + j];
        int q = j/6, ow = j%6;
        int co = q*64 + lane2;
        rb[(((size_t)(b*256+co)*5 + od)*6 + oh)*6 + ow] = s;
    }
}

// conv2 BN stats from raw interior (16 buffers) + analytic background class counts
__global__ __launch_bounds__(64) void k_stats_c2(const float* __restrict__ raw2, const float* __restrict__ bgraw2,
                                                 const float* __restrict__ cb2, const float* __restrict__ cg2,
                                                 const float* __restrict__ cbe2, float* __restrict__ ACb2){
    int o = blockIdx.x;
    int lane = threadIdx.x;
    float s=0.f, ss=0.f;
    for (int idx=lane; idx<360; idx+=64){
        int b = idx/180; int p = idx%180;
        int d = p/36; int rem = p%36; int h = rem/6; int w = rem%6;
        size_t base = (((size_t)(b*256+o)*5 + d)*6 + h)*6 + w;
        float v = 0.f;
        #pragma unroll
        for (int q=0;q<16;q++) v += raw2[q*92160+base];
        s += v; ss += v*v;
    }
    #pragma unroll
    for (int off=32; off>0; off>>=1){ s += __shfl_down(s,off); ss += __shfl_down(ss,off); }
    if (lane==0){
        const int n2[8] = {3744,104,104,0,936,26,26,0};   // per batch; x2 batches
        float bgv[8];
        #pragma unroll
        for (int c=0;c<8;c++){ bgv[c]=bgraw2[o*8+c]; s += 2.f*n2[c]*bgv[c]; ss += 2.f*n2[c]*bgv[c]*bgv[c]; }
        const float N = 10240.f;
        float b = cb2[o];
        float sum_y = s + N*b;
        float ssq_y = ss + 2.f*b*s + N*b*b;
        float m = sum_y/N;
        float var = ssq_y/N - m*m;
        float A = cg2[o]*rsqrtf(var+EPS); float C = cbe2[o] - m*A;
        ACb2[o]=A; ACb2[256+o]=C;
        for (int c=0;c<8;c++) ACb2[512+o*8+c] = fmaxf((bgv[c]+b)*A + C, 0.f);
    }
}

// I2p[b][ci][7][9][12]
__global__ void k_fill_I2(const float* __restrict__ raw2, const float* __restrict__ ACb2,
                          const float* __restrict__ cb2, float* __restrict__ I2p){
    int i = blockIdx.x*blockDim.x + threadIdx.x;   // grid exactly 387,072
    int wpad = i % 12; int r = i / 12;
    int hpad = r % 9; r /= 9;
    int dpad = r % 7; r /= 7;
    int ci = r % 256; int b = r / 256;
    float val;
    if (dpad==0 || dpad==6 || hpad==0 || wpad==0 || wpad>8) val = 0.f;
    else {
        int d = dpad-1, h = hpad-1, w = wpad-1;
        if (h<6 && w<6){
            size_t idx = (((size_t)(b*256+ci)*5 + d)*6 + h)*6 + w;
            float raw = 0.f;
            #pragma unroll
            for (int q=0;q<16;q++) raw += raw2[q*92160+idx];
            val = fmaxf((raw + cb2[ci])*ACb2[ci] + ACb2[256+ci], 0.f);
        } else {
            int cls = ((d==0)?4:0) | ((h==0)?2:0) | ((w==0)?1:0);
            val = ACb2[512 + ci*8 + cls];
        }
    }
    I2p[i] = val;
}

// conv3 background classes: bgraw3[o][12]; coalesced via wT3
__global__ __launch_bounds__(256) void k_bg3(const float* __restrict__ wT3, const float* __restrict__ ACb2,
                                             float* __restrict__ bgraw3){
    int o = threadIdx.x;
    int ci0 = blockIdx.x*8;
    float acc[12];
    #pragma unroll
    for (int c=0;c<12;c++) acc[c]=0.f;
    for (int ci=ci0; ci<ci0+8; ci++){
        float w[27];
        const float* wp = wT3 + (size_t)ci*27*256 + o;
        #pragma unroll
        for (int t=0;t<27;t++) w[t] = wp[t*256];
        const float* bg = ACb2 + 512 + ci*8;
        float bgv[8];
        #pragma unroll
        for (int q=0;q<8;q++) bgv[q]=bg[q];
        #pragma unroll
        for (int c=0;c<12;c++){
            const int odc = c>>2; const int h0 = (c>>1)&1; const int w0 = c&1;
            float sum = 0.f;
            #pragma unroll
            for (int kd=0;kd<3;kd++){
                const int d = 2*odc-1+kd; if (d<0||d>=5) continue;
                const int db = (d==0)?4:0;
                #pragma unroll
                for (int kh=0;kh<3;kh++){
                    if (h0 && kh==0) continue;
                    const int hb = (h0 && kh==1)?2:0;
                    #pragma unroll
                    for (int kw=0;kw<3;kw++){
                        if (w0 && kw==0) continue;
                        const int wb = (w0 && kw==1)?1:0;
                        sum += bgv[db|hb|wb]*w[(kd*3+kh)*3+kw];
                    }
                }
            }
            acc[c] += sum;
        }
    }
    #pragma unroll
    for (int c=0;c<12;c++) atomicAdd(&bgraw3[o*12+c], acc[c]);
}

// conv3: grid 768 = ((b*3+od)*4+oh)*32+ciq ; 256 thr = 4 waves x 2 ci; LDS reduce -> store buf[ciq]
__global__ __launch_bounds__(256) void k_conv3(const float* __restrict__ I2p, const float* __restrict__ wT3,
                                               float* __restrict__ raw3){
    int blk = blockIdx.x;
    int ciq = blk & 31; blk >>= 5;
    int oh = blk % 4; blk /= 4;
    int od = blk % 3; int b = blk / 3;
    int wave = threadIdx.x >> 6, lane = threadIdx.x & 63;
    float acc[4][4];
    #pragma unroll
    for (int q=0;q<4;q++)
        #pragma unroll
        for (int i=0;i<4;i++) acc[q][i]=0.f;
    int ci0 = ciq*8 + wave*2;
    for (int ci = ci0; ci < ci0+2; ci++){
        const float* base = I2p + ((size_t)(b*256+ci)*7 + 2*od)*108 + (2*oh)*12;
        const float* wp0 = wT3 + (size_t)ci*27*256 + lane;
        #pragma unroll
        for (int kd=0;kd<3;kd++){
            #pragma unroll
            for (int kh=0;kh<3;kh++){
                float row[12];
                const float4* rp = (const float4*)(base + kd*108 + kh*12);
                #pragma unroll
                for (int i=0;i<3;i++){ float4 t=rp[i]; row[4*i]=t.x; row[4*i+1]=t.y; row[4*i+2]=t.z; row[4*i+3]=t.w; }
                const float* wp = wp0 + (kd*3+kh)*3*256;
                #pragma unroll
                for (int kw=0;kw<3;kw++){
                    float w0=wp[kw*256], w1=wp[kw*256+64], w2v=wp[kw*256+128], w3=wp[kw*256+192];
                    #pragma unroll
                    for (int ow=0;ow<4;ow++){
                        float x = row[2*ow+kw];
                        acc[0][ow]+=x*w0; acc[1][ow]+=x*w1; acc[2][ow]+=x*w2v; acc[3][ow]+=x*w3;
                    }
                }
            }
        }
    }
    __shared__ float red[4*1028];
    #pragma unroll
    for (int q=0;q<4;q++)
        #pragma unroll
        for (int ow=0;ow<4;ow++) red[wave*1028 + lane*16 + q*4 + ow] = acc[q][ow];
    __syncthreads();
    float* rb = raw3 + (size_t)ciq*24576;
    for (int idx = threadIdx.x; idx < 1024; idx += 256){
        int lane2 = idx/16, j = idx%16;
        float s = red[0*1028 + lane2*16 + j] + red[1*1028 + lane2*16 + j]
                + red[2*1028 + lane2*16 + j] + red[3*1028 + lane2*16 + j];
        int q = j/4, ow = j%4;
        int co = q*64 + lane2;
        rb[(((size_t)(b*256+co)*3 + od)*4 + oh)*4 + ow] = s;
    }
}

// conv3 BN stats from raw interior (32 buffers) + analytic class counts
__global__ __launch_bounds__(64) void k_stats_c3(const float* __restrict__ raw3, const float* __restrict__ bgraw3,
                                                 const float* __restrict__ cb3, const float* __restrict__ cg3,
                                                 const float* __restrict__ cbe3, float* __restrict__ AC3){
    int o = blockIdx.x;
    int lane = threadIdx.x;
    float s=0.f, ss=0.f;
    for (int idx=lane; idx<96; idx+=64){
        int b = idx/48; int p = idx%48;
        int d = p/16; int rem = p%16; int h = rem/4; int w = rem%4;
        size_t base = (((size_t)(b*256+o)*3 + d)*4 + h)*4 + w;
        float v = 0.f;
        #pragma unroll
        for (int q=0;q<32;q++) v += raw3[q*24576+base];
        s += v; ss += v*v;
    }
    #pragma unroll
    for (int off=32; off>0; off>>=1){ s += __shfl_down(s,off); ss += __shfl_down(ss,off); }
    if (lane==0){
        const int n3hw[4] = {216,12,12,0};   // per (b,od)
        for (int c=0;c<12;c++){
            float bg = bgraw3[o*12+c];
            float n = 2.f*n3hw[c&3];
            s += n*bg; ss += n*bg*bg;
        }
        const float N = 1536.f;
        float b = cb3[o];
        float sum_y = s + N*b;
        float ssq_y = ss + 2.f*b*s + N*b*b;
        float m = sum_y/N;
        float var = ssq_y/N - m*m;
        float A = cg3[o]*rsqrtf(var+EPS);
        AC3[o]=A; AC3[256+o]=cbe3[o] - m*A;
    }
}

// final output directly from raw3/bg3
__global__ void k_final(const float* __restrict__ raw3, const float* __restrict__ bgraw3,
                        const float* __restrict__ cb3, const float* __restrict__ AC3,
                        float* __restrict__ out){
    int i = blockIdx.x*blockDim.x + threadIdx.x;
    if (i >= 2*256*3*16*16) return;
    int ow = i % 16; int r = i / 16;
    int oh = r % 16; r /= 16;
    int od = r % 3; r /= 3;
    int o = r % 256; int b = r / 256;
    float v;
    if (oh<4 && ow<4){
        size_t base = (((size_t)(b*256+o)*3 + od)*4 + oh)*4 + ow;
        v = 0.f;
        #pragma unroll
        for (int q=0;q<32;q++) v += raw3[q*24576+base];
    } else {
        v = bgraw3[o*12 + od*4 + ((oh==0)?2:0) + ((ow==0)?1:0)];
    }
    out[i] = fmaxf((v + cb3[o])*AC3[o] + AC3[256+o], 0.f);
}

// ================= launch =================

extern "C" void kernel_launch(void* const* d_in, const int* in_sizes, int n_in,
                              void* d_out, int out_size, void* d_ws, size_t ws_size,
                              hipStream_t stream) {
    const float* vf    = (const float*)d_in[0];
    const int*   coords= (const int*)d_in[1];
    const float* w1    = (const float*)d_in[5];
    const float* b1    = (const float*)d_in[6];
    const float* g1    = (const float*)d_in[7];
    const float* be1   = (const float*)d_in[8];
    const float* w2    = (const float*)d_in[9];
    const float* b2    = (const float*)d_in[10];
    const float* g2    = (const float*)d_in[11];
    const float* be2   = (const float*)d_in[12];
    const float* cw1   = (const float*)d_in[13];
    const float* cb1   = (const float*)d_in[14];
    const float* cg1   = (const float*)d_in[15];
    const float* cbe1  = (const float*)d_in[16];
    const float* cw2   = (const float*)d_in[17];
    const float* cb2   = (const float*)d_in[18];
    const float* cg2   = (const float*)d_in[19];
    const float* cbe2  = (const float*)d_in[20];
    const float* cw3   = (const float*)d_in[21];
    const float* cb3   = (const float*)d_in[22];
    const float* cg3   = (const float*)d_in[23];
    const float* cbe3  = (const float*)d_in[24];
    float* out = (float*)d_out;
    float* ws  = (float*)d_ws;
    __hip_bfloat16* I0cl = (__hip_bfloat16*)(ws + OFF_I0CL);
    __hip_bfloat16* wT1b = (__hip_bfloat16*)(ws + OFF_WT1B);

    hipMemsetAsync(ws + OFF_SX,  0,    4192*4, stream);        // SX + MST
    hipMemsetAsync(ws + OFF_BG2, 0,    5120*4, stream);        // BG2 + BG3
    hipMemsetAsync(ws + OFF_WIN, 0xFF, 16000*4, stream);
    hipMemsetAsync(ws + OFF_I0CL, 0, 1485824ull*4, stream);    // bf16 I0cl (incl slack)

    k_t_tile<<<777,256,0,stream>>>(cw2, cw3, w2, cw1, ws+OFF_WT2, ws+OFF_WT3, ws+OFF_W2T, wT1b);
    k_stats_x<<<768,256,0,stream>>>(vf, ws+OFF_SX);
    k_ac1<<<1,64,0,stream>>>(ws+OFF_SX, w1,b1,g1,be1, ws+OFF_AC1);
    k_vfe1<<<6000,256,0,stream>>>(vf, w1, ws+OFF_AC1, ws+OFF_F1);
    k_stats_f1<<<256,256,0,stream>>>(ws+OFF_F1, ws+OFF_MSTP);
    k_red_mst<<<65,64,0,stream>>>(ws+OFF_MSTP, ws+OFF_MST);
    k_ac2<<<128,64,0,stream>>>(ws+OFF_MST, w2,b2,g2,be2, ws+OFF_AC2);
    k_scatter<<<94,256,0,stream>>>(coords, (int*)(ws+OFF_WIN));
    k_I0<<<800,256,0,stream>>>((int*)(ws+OFF_WIN), ws+OFF_F1, ws+OFF_W2T, ws+OFF_AC2, I0cl);
    k_conv1m<<<1760,256,0,stream>>>(I0cl, wT1b, ws+OFF_RAW1);
    k_stats_c1<<<128,256,0,stream>>>(ws+OFF_RAW1, cb1,cg1,cbe1, ws+OFF_ACB1);
    k_fill_I1<<<2288,256,0,stream>>>(ws+OFF_RAW1, ws+OFF_ACB1, cb1, ws+OFF_I1);
    k_bg2<<<16,256,0,stream>>>(ws+OFF_WT2, ws+OFF_ACB1, ws+OFF_BG2);
    k_conv2<<<960,256,0,stream>>>(ws+OFF_I1, ws+OFF_WT2, ws+OFF_RAW2);
    k_stats_c2<<<256,64,0,stream>>>(ws+OFF_RAW2, ws+OFF_BG2, cb2, cg2, cbe2, ws+OFF_ACB2);
    k_fill_I2<<<1512,256,0,stream>>>(ws+OFF_RAW2, ws+OFF_ACB2, cb2, ws+OFF_I2);
    k_bg3<<<32,256,0,stream>>>(ws+OFF_WT3, ws+OFF_ACB2, ws+OFF_BG3);
    k_conv3<<<768,256,0,stream>>>(ws+OFF_I2, ws+OFF_WT3, ws+OFF_RAW3);
    k_stats_c3<<<256,64,0,stream>>>(ws+OFF_RAW3, ws+OFF_BG3, cb3, cg3, cbe3, ws+OFF_AC3);
    k_final<<<1536,256,0,stream>>>(ws+OFF_RAW3, ws+OFF_BG3, cb3, ws+OFF_AC3, out);
}

// Round 11
// 387.638 us; speedup vs baseline: 1.1253x; 1.0011x over previous
//
#include <hip/hip_runtime.h>
#include <hip/hip_bf16.h>

#define EPS 1e-5f

// ---- problem dims ----
#define BB 2
#define NV 12000
#define NP 32
#define CIN 5
#define GD 20
// conv1: active out 10x11x11; conv2 region 5x6x6; conv3 region 3x4x4

typedef __attribute__((ext_vector_type(8))) short bf16x8;
typedef __attribute__((ext_vector_type(4))) float f32x4;

// ---- workspace layout (float offsets) ----
static const size_t OFF_SX   = 0;         // 32
static const size_t OFF_MST  = 32;        // 4160   [memset0: 0..4192]
static const size_t OFF_AC1  = 4192;      // 128
static const size_t OFF_AC2  = 4320;      // 256
static const size_t OFF_ACB1 = 4576;      // 384  (A[128],C[128],bg1[128])
static const size_t OFF_ACB2 = 4960;      // 2560 (A[256],C[256],bgn2[256*8])
static const size_t OFF_AC3  = 7520;      // 512
static const size_t OFF_BG2  = 8032;      // 2048   [memset1: 8032..13152]
static const size_t OFF_BG3  = 10080;     // 3072
static const size_t OFF_W2T  = 13152;     // 8192
static const size_t OFF_WIN  = 21344;     // 16000 ints [memset 0xFF]
static const size_t OFF_F1   = 37344;     // 1,536,000
static const size_t OFF_I0CL = 1573344;   // bf16 [b][21][23][24][128ci] (+slack) = 1,485,824 floats (memset 0)
static const size_t OFF_I1   = 3059168;   // 585,728   [b][ci][11][13][16]
static const size_t OFF_I2   = 3644896;   // 387,072   [b][ci][7][9][12]
static const size_t OFF_WT1B = 4031968;   // bf16 [27][128co][128ci] = 221,184 floats
static const size_t OFF_WT2  = 4253152;   // 884,736
static const size_t OFF_WT3  = 5137888;   // 1,769,472
static const size_t OFF_RAW1 = 6907360;   // 4 x 309,760
static const size_t OFF_RAW2 = 8146400;   // 16 x 92,160
static const size_t OFF_RAW3 = 9620960;   // 32 x 24,576
static const size_t OFF_MSTP = 10407392;  // 256 x 4160 partials (no memset needed; fully written)
// end = 11,472,352 floats = 45.9 MB

// ================= VFE stage =================

// LDS-staged fully-coalesced moment accumulation: block chunk = 5120 floats (1024 points)
__global__ __launch_bounds__(256) void k_stats_x(const float* __restrict__ vf, float* __restrict__ out) {
    __shared__ float st[5120];
    __shared__ float sh[20];
    int t = threadIdx.x;
    const float4* src = (const float4*)(vf + (size_t)blockIdx.x*5120);
    #pragma unroll
    for (int i=0;i<5;i++){
        ((float4*)st)[i*256 + t] = src[i*256 + t];
    }
    if (t < 20) sh[t]=0.f;
    __syncthreads();
    float ls[5] = {0,0,0,0,0};
    float lq[15];
    #pragma unroll
    for (int i=0;i<15;i++) lq[i]=0.f;
    const float* base = st + t*20;
    #pragma unroll
    for (int p=0;p<4;p++){
        const float* v = base + p*5;
        int k=0;
        #pragma unroll
        for (int c=0;c<5;c++){
            ls[c]+=v[c];
            #pragma unroll
            for(int c2=c;c2<5;c2++){ lq[k++]+=v[c]*v[c2]; }
        }
    }
    #pragma unroll
    for (int c=0;c<5;c++) atomicAdd(&sh[c], ls[c]);
    #pragma unroll
    for (int k=0;k<15;k++) atomicAdd(&sh[5+k], lq[k]);
    __syncthreads();
    if (t<20) atomicAdd(&out[t], sh[t]);
}

__global__ void k_ac1(const float* __restrict__ stats, const float* __restrict__ w1,
                      const float* __restrict__ b1, const float* __restrict__ g1,
                      const float* __restrict__ be1, float* __restrict__ AC1){
    int o = threadIdx.x; if (o>=64) return;
    const float N = (float)(BB*NV*NP);
    float w[5];
    #pragma unroll
    for(int c=0;c<5;c++) w[c]=w1[o*5+c];
    float b=b1[o];
    float wd=0;
    #pragma unroll
    for(int c=0;c<5;c++) wd += w[c]*stats[c];
    float m = wd/N + b;
    float q=0; int kk=5;
    for(int c=0;c<5;c++) for(int c2=c;c2<5;c2++){ float s=stats[kk++]; q += (c==c2?1.f:2.f)*w[c]*w[c2]*s; }
    q = q/N + 2.f*b*wd/N + b*b;
    float var = q - m*m;
    float A = g1[o]*rsqrtf(var + EPS);
    AC1[o] = A;
    AC1[64+o] = be1[o] + (b - m)*A;
}

__global__ __launch_bounds__(256) void k_vfe1(const float* __restrict__ vf, const float* __restrict__ w1,
                                              const float* __restrict__ AC1, float* __restrict__ f1){
    int wave = threadIdx.x >> 6;
    int lane = threadIdx.x & 63;
    int v = blockIdx.x*4 + wave;
    if (v >= BB*NV) return;
    float w[5];
    #pragma unroll
    for (int c=0;c<5;c++) w[c] = w1[lane*5+c];
    float A = AC1[lane], Cc = AC1[64+lane];
    const float* x = vf + (size_t)v*(NP*CIN);
    float mx = -1e30f;
    #pragma unroll
    for (int pc = 0; pc < 8; pc++) {
        float xx[20];
        const float4* x4 = (const float4*)(x + pc*20);
        #pragma unroll
        for (int i=0;i<5;i++){ float4 t = x4[i]; xx[4*i]=t.x; xx[4*i+1]=t.y; xx[4*i+2]=t.z; xx[4*i+3]=t.w; }
        #pragma unroll
        for (int j=0;j<4;j++){
            float y = xx[j*5]*w[0]+xx[j*5+1]*w[1]+xx[j*5+2]*w[2]+xx[j*5+3]*w[3]+xx[j*5+4]*w[4];
            mx = fmaxf(mx, y*A + Cc);
        }
    }
    f1[(size_t)v*64 + lane] = fmaxf(mx, 0.f);
}

// atomic-free: each block writes its 4160-float accumulator to a private partial slice
__global__ __launch_bounds__(256) void k_stats_f1(const float* __restrict__ f1, float* __restrict__ Mpart){
    __shared__ float tile[16][64];
    __shared__ float ssum[64];
    int t = threadIdx.x;
    if (t < 64) ssum[t]=0.f;
    float acc[4][4];
    #pragma unroll
    for(int i=0;i<4;i++)
        #pragma unroll
        for(int j=0;j<4;j++) acc[i][j]=0.f;
    int i4 = (t>>4)*4, j4 = (t&15)*4;
    const int NT = (BB*NV)/16; // 1500
    for (int tl = blockIdx.x; tl < NT; tl += gridDim.x) {
        __syncthreads();
        for (int i = t; i < 16*64; i += 256) tile[i>>6][i&63] = f1[(size_t)tl*1024 + i];
        __syncthreads();
        #pragma unroll
        for (int r=0;r<16;r++){
            float a[4], bb[4];
            #pragma unroll
            for (int u=0;u<4;u++) a[u]=tile[r][i4+u];
            #pragma unroll
            for (int u=0;u<4;u++) bb[u]=tile[r][j4+u];
            #pragma unroll
            for (int u=0;u<4;u++)
                #pragma unroll
                for (int q=0;q<4;q++) acc[u][q] += a[u]*bb[q];
        }
        if (t < 64) {
            float s=0;
            #pragma unroll
            for(int r=0;r<16;r++) s+=tile[r][t];
            ssum[t]+=s;
        }
    }
    float* mp = Mpart + (size_t)blockIdx.x*4160;
    #pragma unroll
    for(int i=0;i<4;i++)
        #pragma unroll
        for(int j=0;j<4;j++) mp[(size_t)(i4+i)*64 + (j4+j)] = acc[i][j];
    __syncthreads();
    if (t<64) mp[4096 + t] = ssum[t];
}

// reduce 256 partial slices -> Mst[4160]
__global__ __launch_bounds__(64) void k_red_mst(const float* __restrict__ Mpart, float* __restrict__ Mst){
    int e = blockIdx.x*64 + threadIdx.x;
    if (e >= 4160) return;
    float s = 0.f;
    #pragma unroll 8
    for (int p=0;p<256;p++) s += Mpart[(size_t)p*4160 + e];
    Mst[e] = s;
}

// parallel ac2: one block per o (128 blocks x 64 lanes)
__global__ __launch_bounds__(64) void k_ac2(const float* __restrict__ Mst, const float* __restrict__ w2,
                                            const float* __restrict__ b2, const float* __restrict__ g2,
                                            const float* __restrict__ be2, float* __restrict__ AC2){
    int o = blockIdx.x;
    int j = threadIdx.x;
    const float N = (float)(BB*NV);
    const float* M = Mst; const float* sv = Mst+4096;
    const float* wrow = w2 + o*64;
    float wj = wrow[j];
    float sj = 0.f;
    #pragma unroll 8
    for (int c=0;c<64;c++) sj += wrow[c]*M[c*64+j];
    float q = wj*sj;
    float wdp = wj*sv[j];
    #pragma unroll
    for (int off=32; off>0; off>>=1){ q += __shfl_down(q,off); wdp += __shfl_down(wdp,off); }
    if (j==0){
        float b = b2[o];
        float m = wdp/N + b;
        float qq = q/N + 2.f*b*wdp/N + b*b;
        float var = qq - m*m;
        float A = g2[o]*rsqrtf(var+EPS);
        AC2[o]=A; AC2[128+o]= be2[o] + (b-m)*A;
    }
}

// ================= scatter =================

__global__ void k_scatter(const int* __restrict__ coords, int* __restrict__ winner){
    int i = blockIdx.x*blockDim.x+threadIdx.x;
    if (i >= BB*NV) return;
    int b = i / NV, n = i % NV;
    int d = coords[(size_t)i*3], h = coords[(size_t)i*3+1], w = coords[(size_t)i*3+2];
    if (d<0||d>=GD||h<0||h>=GD||w<0||w>=GD) return;
    atomicMax(&winner[b*8000 + d*400 + h*20 + w], n);
}

// FUSED vfe2 + scatter-fill into channels-last bf16 I0cl[b][21][23][24][128].
__global__ __launch_bounds__(256) void k_I0(const int* __restrict__ winner, const float* __restrict__ f1,
                                            const float* __restrict__ w2T, const float* __restrict__ AC2,
                                            __hip_bfloat16* __restrict__ I0cl){
    int blk = blockIdx.x;
    int b = blk / 400; int dh = blk % 400;
    int d = dh / 20, h = dh % 20;
    __shared__ int win[20];
    __shared__ float f1sh[20][64];
    __shared__ float sh[20*128];   // [w][ci]
    int t = threadIdx.x;
    if (t < 20) win[t] = winner[b*8000 + dh*20 + t];
    __syncthreads();
    for (int idx = t; idx < 1280; idx += 256){
        int cell = idx >> 6, c = idx & 63;
        int n = win[cell];
        f1sh[cell][c] = (n>=0) ? f1[((size_t)(b*NV+n))*64 + c] : 0.f;
    }
    __syncthreads();
    int o = t & 127;
    int half = t >> 7;
    float A = AC2[o], C = AC2[128+o];
    for (int p=0;p<10;p++){
        int cell = p*2 + half;
        float acc = 0.f;
        if (win[cell] >= 0){
            #pragma unroll
            for (int c=0;c<64;c++) acc += f1sh[cell][c]*w2T[c*128+o];
            acc = fmaxf(acc*A + C, 0.f);
        }
        sh[cell*128 + o] = acc;
    }
    __syncthreads();
    __hip_bfloat16* outp = I0cl + (((size_t)(b*21 + d+1)*23 + h+1)*24 + 1)*128;
    for (int idx = t; idx < 2560; idx += 256) outp[idx] = __float2bfloat16(sh[idx]);
}

// ================= merged weight prep =================
// blocks 0..215: wT2 tiles; 216..647: wT3 tiles; 648: w2T; 649..776: wT1b (bf16 pack, co = blk-649)
__global__ __launch_bounds__(256) void k_t_tile(const float* __restrict__ cw2, const float* __restrict__ cw3,
                                                const float* __restrict__ w2, const float* __restrict__ cw1,
                                                float* __restrict__ wT2, float* __restrict__ wT3,
                                                float* __restrict__ w2T, __hip_bfloat16* __restrict__ wT1b){
    int blk = blockIdx.x;
    if (blk >= 649){
        int co = blk - 649;
        __shared__ float tlw[3456];
        int t = threadIdx.x;
        for (int j=t; j<3456; j+=256) tlw[j] = cw1[(size_t)co*3456 + j];   // j = ci*27+tap
        __syncthreads();
        for (int idx=t; idx<3456; idx+=256){
            int tap = idx >> 7, ci = idx & 127;
            wT1b[((size_t)(tap*128 + co) << 7) + ci] = __float2bfloat16(tlw[ci*27 + tap]);
        }
        return;
    }
    if (blk == 648){
        for (int i=threadIdx.x; i<8192; i+=256){ int o=i>>6, c=i&63; w2T[c*128+o]=w2[i]; }
        return;
    }
    const float* src; float* dst; int CO, R;
    if (blk < 216){ src=cw2; dst=wT2; CO=256; R=3456; }
    else { blk-=216; src=cw3; dst=wT3; CO=256; R=6912; }
    int nrt = R/64;
    int rt = blk % nrt, ct = blk / nrt;
    int r0 = rt*64, c0 = ct*64;
    __shared__ float tl[64][65];
    int tj = threadIdx.x & 63;
    int ti0 = threadIdx.x >> 6;
    #pragma unroll
    for (int k=0;k<16;k++){
        int i = ti0 + k*4;
        tl[i][tj] = src[(size_t)(c0+i)*R + r0 + tj];
    }
    __syncthreads();
    #pragma unroll
    for (int k=0;k<16;k++){
        int j = ti0 + k*4;
        dst[(size_t)(r0+j)*CO + c0 + tj] = tl[tj][j];
    }
}

// ================= conv1 via MFMA (bf16 implicit GEMM) =================
// grid 1760 = ((b*10+od)*11+oh)*8 + coq ; 4 waves = kq (K-slices of 32 ci); each wave 27 MFMA.
__global__ __launch_bounds__(256) void k_conv1m(const __hip_bfloat16* __restrict__ I0cl,
                                                const __hip_bfloat16* __restrict__ wT1b,
                                                float* __restrict__ raw1){
    int blk = blockIdx.x;
    int coq = blk & 7; blk >>= 3;
    int oh = blk % 11; blk /= 11;
    int od = blk % 10; int b = blk / 10;
    int kq = threadIdx.x >> 6, lane = threadIdx.x & 63;
    int col = lane & 15, quad = lane >> 4;
    int co0 = coq*16;
    int ci_base = kq*32 + quad*8;
    f32x4 acc = {0.f,0.f,0.f,0.f};
    const __hip_bfloat16* Bb = I0cl + (size_t)b*21*23*24*128 + (2*col)*128 + ci_base;
    const __hip_bfloat16* Ab = wT1b + (size_t)(co0 + col)*128 + ci_base;
    #pragma unroll 3
    for (int tap=0; tap<27; tap++){
        int kd = tap/9, kh = (tap/3)%3, kw = tap%3;
        int d = 2*od + kd, h = 2*oh + kh;     // padded indices
        const __hip_bfloat16* bp = Bb + ((size_t)(d*23 + h)*24 + kw)*128;
        const __hip_bfloat16* ap = Ab + (size_t)tap*16384;
        bf16x8 a0 = *(const bf16x8*)ap;
        bf16x8 b0 = *(const bf16x8*)bp;
        acc = __builtin_amdgcn_mfma_f32_16x16x32_bf16(a0, b0, acc, 0, 0, 0);
    }
    if (col < 11){
        #pragma unroll
        for (int r=0;r<4;r++){
            int co = co0 + quad*4 + r;
            raw1[(size_t)kq*309760 + (((size_t)(b*128+co)*10 + od)*11 + oh)*11 + col] = acc[r];
        }
    }
}

// stats for conv1 (zero background), sums 4 K-split buffers
__global__ __launch_bounds__(256) void k_stats_c1(const float* __restrict__ raw1, const float* __restrict__ cb,
                                                  const float* __restrict__ cg, const float* __restrict__ cbe,
                                                  float* __restrict__ ACb1){
    int co = blockIdx.x;
    float s=0, ss=0;
    for (int b=0;b<2;b++){
        size_t base = ((size_t)(b*128+co))*1210;
        for (int i=threadIdx.x; i<1210; i+=256){
            float v = raw1[base+i] + raw1[309760+base+i] + raw1[2*309760+base+i] + raw1[3*309760+base+i];
            s+=v; ss+=v*v;
        }
    }
    __shared__ float sh1[256], sh2[256];
    sh1[threadIdx.x]=s; sh2[threadIdx.x]=ss; __syncthreads();
    for (int st=128; st>0; st>>=1){
        if (threadIdx.x<st){ sh1[threadIdx.x]+=sh1[threadIdx.x+st]; sh2[threadIdx.x]+=sh2[threadIdx.x+st]; }
        __syncthreads();
    }
    if (threadIdx.x==0){
        float bias = cb[co];
        const float N = 81920.f;   // 2*10*64*64
        float sum_y = sh1[0] + N*bias;
        float ssq_y = sh2[0] + 2.f*bias*sh1[0] + N*bias*bias;
        float m = sum_y/N;
        float var = ssq_y/N - m*m;
        float A = cg[co]*rsqrtf(var+EPS);
        float C = cbe[co] - m*A;
        ACb1[co]=A; ACb1[128+co]=C;
        ACb1[256+co]=fmaxf(bias*A + C, 0.f);  // bg1
    }
}

// I1p[b][ci][11][13][16]
__global__ void k_fill_I1(const float* __restrict__ raw1, const float* __restrict__ ACb1,
                          const float* __restrict__ cb, float* __restrict__ I1p){
    int i = blockIdx.x*blockDim.x + threadIdx.x;   // grid exactly 585,728
    int wpad = i % 16; int r = i / 16;
    int hpad = r % 13; r /= 13;
    int dpad = r % 11; r /= 11;
    int ci = r % 128; int b = r / 128;
    float val;
    if (dpad==0 || hpad==0 || wpad==0 || wpad>12) val = 0.f;
    else {
        int d = dpad-1, h = hpad-1, w = wpad-1;
        if (h < 11 && w < 11){
            size_t idx = (((size_t)(b*128+ci)*10 + d)*11 + h)*11 + w;
            float raw = raw1[idx] + raw1[309760+idx] + raw1[2*309760+idx] + raw1[3*309760+idx];
            val = fmaxf((raw + cb[ci])*ACb1[ci] + ACb1[128+ci], 0.f);
        } else val = ACb1[256+ci];
    }
    I1p[i] = val;
}

// conv2 background class constants: bgraw2[o][8]; coalesced via wT2
__global__ __launch_bounds__(256) void k_bg2(const float* __restrict__ wT2, const float* __restrict__ ACb1,
                                             float* __restrict__ bgraw2){
    int o = threadIdx.x;
    int ci0 = blockIdx.x*8;
    float acc[8];
    #pragma unroll
    for (int c=0;c<8;c++) acc[c]=0.f;
    for (int ci=ci0; ci<ci0+8; ci++){
        float w[27];
        const float* wp = wT2 + (size_t)ci*27*256 + o;
        #pragma unroll
        for (int t=0;t<27;t++) w[t] = wp[t*256];
        float bg = ACb1[256+ci];
        float sw0[9], sw1[9];
        #pragma unroll
        for (int t9=0;t9<9;t9++){ sw1[t9]=w[3*t9+1]+w[3*t9+2]; sw0[t9]=w[3*t9]+sw1[t9]; }
        #pragma unroll
        for (int cls=0; cls<8; cls++){
            const int d0=(cls>>2)&1, h0=(cls>>1)&1, w0=cls&1;
            float ws=0.f;
            #pragma unroll
            for (int kd=0;kd<3;kd++){
                if (d0 && kd==0) continue;
                #pragma unroll
                for (int kh=0;kh<3;kh++){
                    if (h0 && kh==0) continue;
                    ws += w0 ? sw1[kd*3+kh] : sw0[kd*3+kh];
                }
            }
            acc[cls] += bg*ws;
        }
    }
    #pragma unroll
    for (int cls=0;cls<8;cls++) atomicAdd(&bgraw2[o*8+cls], acc[cls]);
}

// conv2: grid 960 = ((b*5+od)*6+oh)*16+ciq ; 256 thr = 4 waves x 2 ci; LDS reduce -> store buf[ciq]
__global__ __launch_bounds__(256) void k_conv2(const float* __restrict__ I1p, const float* __restrict__ wT2,
                                               float* __restrict__ raw2){
    int blk = blockIdx.x;
    int ciq = blk & 15; blk >>= 4;
    int oh = blk % 6; blk /= 6;
    int od = blk % 5; int b = blk / 5;
    int wave = threadIdx.x >> 6, lane = threadIdx.x & 63;
    float acc[4][6];
    #pragma unroll
    for (int q=0;q<4;q++)
        #pragma unroll
        for (int i=0;i<6;i++) acc[q][i]=0.f;
    int ci0 = ciq*8 + wave*2;
    for (int ci = ci0; ci < ci0+2; ci++){
        const float* base = I1p + ((size_t)(b*128+ci)*11 + 2*od)*208 + (2*oh)*16;
        const float* wp0 = wT2 + (size_t)ci*27*256 + lane;
        #pragma unroll
        for (int kd=0;kd<3;kd++){
            #pragma unroll
            for (int kh=0;kh<3;kh++){
                float row[16];
                const float4* rp = (const float4*)(base + kd*208 + kh*16);
                #pragma unroll
                for (int i=0;i<4;i++){ float4 t=rp[i]; row[4*i]=t.x; row[4*i+1]=t.y; row[4*i+2]=t.z; row[4*i+3]=t.w; }
                const float* wp = wp0 + (kd*3+kh)*3*256;
                #pragma unroll
                for (int kw=0;kw<3;kw++){
                    float w0=wp[kw*256], w1=wp[kw*256+64], w2v=wp[kw*256+128], w3=wp[kw*256+192];
                    #pragma unroll
                    for (int ow=0;ow<6;ow++){
                        float x = row[2*ow+kw];
                        acc[0][ow]+=x*w0; acc[1][ow]+=x*w1; acc[2][ow]+=x*w2v; acc[3][ow]+=x*w3;
                    }
                }
            }
        }
    }
    __shared__ float red[4*1540];
    #pragma unroll
    for (int q=0;q<4;q++)
        #pragma unroll
        for (int ow=0;ow<6;ow++) red[wave*1540 + lane*24 + q*6 + ow] = acc[q][ow];
    __syncthreads();
    float* rb = raw2 + (size_t)ciq*92160;
    for (int idx = threadIdx.x; idx < 1536; idx += 256){
        int lane2 = idx/24, j = idx%24;
        float s = red[0*1540 + lane2*24 + j] + red[1*1540 + lane2*24 + j]
                + red[2*1540 + lane2*24 + j] + red[3*1540 + lane2*24 + j];
        int q = j/6, ow = j%6;
        int co = q*64 + lane2;
        rb[(((size_t)(b*256+co)*5 + od)*6 + oh)*6 + ow] = s;
    }
}

// conv2 BN stats from raw interior (16 buffers) + analytic background class counts
__global__ __launch_bounds__(64) void k_stats_c2(const float* __restrict__ raw2, const float* __restrict__ bgraw2,
                                                 const float* __restrict__ cb2, const float* __restrict__ cg2,
                                                 const float* __restrict__ cbe2, float* __restrict__ ACb2){
    int o = blockIdx.x;
    int lane = threadIdx.x;
    float s=0.f, ss=0.f;
    for (int idx=lane; idx<360; idx+=64){
        int b = idx/180; int p = idx%180;
        int d = p/36; int rem = p%36; int h = rem/6; int w = rem%6;
        size_t base = (((size_t)(b*256+o)*5 + d)*6 + h)*6 + w;
        float v = 0.f;
        #pragma unroll
        for (int q=0;q<16;q++) v += raw2[q*92160+base];
        s += v; ss += v*v;
    }
    #pragma unroll
    for (int off=32; off>0; off>>=1){ s += __shfl_down(s,off); ss += __shfl_down(ss,off); }
    if (lane==0){
        const int n2[8] = {3744,104,104,0,936,26,26,0};   // per batch; x2 batches
        float bgv[8];
        #pragma unroll
        for (int c=0;c<8;c++){ bgv[c]=bgraw2[o*8+c]; s += 2.f*n2[c]*bgv[c]; ss += 2.f*n2[c]*bgv[c]*bgv[c]; }
        const float N = 10240.f;
        float b = cb2[o];
        float sum_y = s + N*b;
        float ssq_y = ss + 2.f*b*s + N*b*b;
        float m = sum_y/N;
        float var = ssq_y/N - m*m;
        float A = cg2[o]*rsqrtf(var+EPS); float C = cbe2[o] - m*A;
        ACb2[o]=A; ACb2[256+o]=C;
        for (int c=0;c<8;c++) ACb2[512+o*8+c] = fmaxf((bgv[c]+b)*A + C, 0.f);
    }
}

// I2p[b][ci][7][9][12]
__global__ void k_fill_I2(const float* __restrict__ raw2, const float* __restrict__ ACb2,
                          const float* __restrict__ cb2, float* __restrict__ I2p){
    int i = blockIdx.x*blockDim.x + threadIdx.x;   // grid exactly 387,072
    int wpad = i % 12; int r = i / 12;
    int hpad = r % 9; r /= 9;
    int dpad = r % 7; r /= 7;
    int ci = r % 256; int b = r / 256;
    float val;
    if (dpad==0 || dpad==6 || hpad==0 || wpad==0 || wpad>8) val = 0.f;
    else {
        int d = dpad-1, h = hpad-1, w = wpad-1;
        if (h<6 && w<6){
            size_t idx = (((size_t)(b*256+ci)*5 + d)*6 + h)*6 + w;
            float raw = 0.f;
            #pragma unroll
            for (int q=0;q<16;q++) raw += raw2[q*92160+idx];
            val = fmaxf((raw + cb2[ci])*ACb2[ci] + ACb2[256+ci], 0.f);
        } else {
            int cls = ((d==0)?4:0) | ((h==0)?2:0) | ((w==0)?1:0);
            val = ACb2[512 + ci*8 + cls];
        }
    }
    I2p[i] = val;
}

// conv3 background classes: bgraw3[o][12]; coalesced via wT3
__global__ __launch_bounds__(256) void k_bg3(const float* __restrict__ wT3, const float* __restrict__ ACb2,
                                             float* __restrict__ bgraw3){
    int o = threadIdx.x;
    int ci0 = blockIdx.x*8;
    float acc[12];
    #pragma unroll
    for (int c=0;c<12;c++) acc[c]=0.f;
    for (int ci=ci0; ci<ci0+8; ci++){
        float w[27];
        const float* wp = wT3 + (size_t)ci*27*256 + o;
        #pragma unroll
        for (int t=0;t<27;t++) w[t] = wp[t*256];
        const float* bg = ACb2 + 512 + ci*8;
        float bgv[8];
        #pragma unroll
        for (int q=0;q<8;q++) bgv[q]=bg[q];
        #pragma unroll
        for (int c=0;c<12;c++){
            const int odc = c>>2; const int h0 = (c>>1)&1; const int w0 = c&1;
            float sum = 0.f;
            #pragma unroll
            for (int kd=0;kd<3;kd++){
                const int d = 2*odc-1+kd; if (d<0||d>=5) continue;
                const int db = (d==0)?4:0;
                #pragma unroll
                for (int kh=0;kh<3;kh++){
                    if (h0 && kh==0) continue;
                    const int hb = (h0 && kh==1)?2:0;
                    #pragma unroll
                    for (int kw=0;kw<3;kw++){
                        if (w0 && kw==0) continue;
                        const int wb = (w0 && kw==1)?1:0;
                        sum += bgv[db|hb|wb]*w[(kd*3+kh)*3+kw];
                    }
                }
            }
            acc[c] += sum;
        }
    }
    #pragma unroll
    for (int c=0;c<12;c++) atomicAdd(&bgraw3[o*12+c], acc[c]);
}

// conv3: grid 768 = ((b*3+od)*4+oh)*32+ciq ; 256 thr = 4 waves x 2 ci; LDS reduce -> store buf[ciq]
__global__ __launch_bounds__(256) void k_conv3(const float* __restrict__ I2p, const float* __restrict__ wT3,
                                               float* __restrict__ raw3){
    int blk = blockIdx.x;
    int ciq = blk & 31; blk >>= 5;
    int oh = blk % 4; blk /= 4;
    int od = blk % 3; int b = blk / 3;
    int wave = threadIdx.x >> 6, lane = threadIdx.x & 63;
    float acc[4][4];
    #pragma unroll
    for (int q=0;q<4;q++)
        #pragma unroll
        for (int i=0;i<4;i++) acc[q][i]=0.f;
    int ci0 = ciq*8 + wave*2;
    for (int ci = ci0; ci < ci0+2; ci++){
        const float* base = I2p + ((size_t)(b*256+ci)*7 + 2*od)*108 + (2*oh)*12;
        const float* wp0 = wT3 + (size_t)ci*27*256 + lane;
        #pragma unroll
        for (int kd=0;kd<3;kd++){
            #pragma unroll
            for (int kh=0;kh<3;kh++){
                float row[12];
                const float4* rp = (const float4*)(base + kd*108 + kh*12);
                #pragma unroll
                for (int i=0;i<3;i++){ float4 t=rp[i]; row[4*i]=t.x; row[4*i+1]=t.y; row[4*i+2]=t.z; row[4*i+3]=t.w; }
                const float* wp = wp0 + (kd*3+kh)*3*256;
                #pragma unroll
                for (int kw=0;kw<3;kw++){
                    float w0=wp[kw*256], w1=wp[kw*256+64], w2v=wp[kw*256+128], w3=wp[kw*256+192];
                    #pragma unroll
                    for (int ow=0;ow<4;ow++){
                        float x = row[2*ow+kw];
                        acc[0][ow]+=x*w0; acc[1][ow]+=x*w1; acc[2][ow]+=x*w2v; acc[3][ow]+=x*w3;
                    }
                }
            }
        }
    }
    __shared__ float red[4*1028];
    #pragma unroll
    for (int q=0;q<4;q++)
        #pragma unroll
        for (int ow=0;ow<4;ow++) red[wave*1028 + lane*16 + q*4 + ow] = acc[q][ow];
    __syncthreads();
    float* rb = raw3 + (size_t)ciq*24576;
    for (int idx = threadIdx.x; idx < 1024; idx += 256){
        int lane2 = idx/16, j = idx%16;
        float s = red[0*1028 + lane2*16 + j] + red[1*1028 + lane2*16 + j]
                + red[2*1028 + lane2*16 + j] + red[3*1028 + lane2*16 + j];
        int q = j/4, ow = j%4;
        int co = q*64 + lane2;
        rb[(((size_t)(b*256+co)*3 + od)*4 + oh)*4 + ow] = s;
    }
}

// conv3 BN stats from raw interior (32 buffers) + analytic class counts
__global__ __launch_bounds__(64) void k_stats_c3(const float* __restrict__ raw3, const float* __restrict__ bgraw3,
                                                 const float* __restrict__ cb3, const float* __restrict__ cg3,
                                                 const float* __restrict__ cbe3, float* __restrict__ AC3){
    int o = blockIdx.x;
    int lane = threadIdx.x;
    float s=0.f, ss=0.f;
    for (int idx=lane; idx<96; idx+=64){
        int b = idx/48; int p = idx%48;
        int d = p/16; int rem = p%16; int h = rem/4; int w = rem%4;
        size_t base = (((size_t)(b*256+o)*3 + d)*4 + h)*4 + w;
        float v = 0.f;
        #pragma unroll
        for (int q=0;q<32;q++) v += raw3[q*24576+base];
        s += v; ss += v*v;
    }
    #pragma unroll
    for (int off=32; off>0; off>>=1){ s += __shfl_down(s,off); ss += __shfl_down(ss,off); }
    if (lane==0){
        const int n3hw[4] = {216,12,12,0};   // per (b,od)
        for (int c=0;c<12;c++){
            float bg = bgraw3[o*12+c];
            float n = 2.f*n3hw[c&3];
            s += n*bg; ss += n*bg*bg;
        }
        const float N = 1536.f;
        float b = cb3[o];
        float sum_y = s + N*b;
        float ssq_y = ss + 2.f*b*s + N*b*b;
        float m = sum_y/N;
        float var = ssq_y/N - m*m;
        float A = cg3[o]*rsqrtf(var+EPS);
        AC3[o]=A; AC3[256+o]=cbe3[o] - m*A;
    }
}

// final output directly from raw3/bg3
__global__ void k_final(const float* __restrict__ raw3, const float* __restrict__ bgraw3,
                        const float* __restrict__ cb3, const float* __restrict__ AC3,
                        float* __restrict__ out){
    int i = blockIdx.x*blockDim.x + threadIdx.x;
    if (i >= 2*256*3*16*16) return;
    int ow = i % 16; int r = i / 16;
    int oh = r % 16; r /= 16;
    int od = r % 3; r /= 3;
    int o = r % 256; int b = r / 256;
    float v;
    if (oh<4 && ow<4){
        size_t base = (((size_t)(b*256+o)*3 + od)*4 + oh)*4 + ow;
        v = 0.f;
        #pragma unroll
        for (int q=0;q<32;q++) v += raw3[q*24576+base];
    } else {
        v = bgraw3[o*12 + od*4 + ((oh==0)?2:0) + ((ow==0)?1:0)];
    }
    out[i] = fmaxf((v + cb3[o])*AC3[o] + AC3[256+o], 0.f);
}

// ================= launch =================

extern "C" void kernel_launch(void* const* d_in, const int* in_sizes, int n_in,
                              void* d_out, int out_size, void* d_ws, size_t ws_size,
                              hipStream_t stream) {
    const float* vf    = (const float*)d_in[0];
    const int*   coords= (const int*)d_in[1];
    const float* w1    = (const float*)d_in[5];
    const float* b1    = (const float*)d_in[6];
    const float* g1    = (const float*)d_in[7];
    const float* be1   = (const float*)d_in[8];
    const float* w2    = (const float*)d_in[9];
    const float* b2    = (const float*)d_in[10];
    const float* g2    = (const float*)d_in[11];
    const float* be2   = (const float*)d_in[12];
    const float* cw1   = (const float*)d_in[13];
    const float* cb1   = (const float*)d_in[14];
    const float* cg1   = (const float*)d_in[15];
    const float* cbe1  = (const float*)d_in[16];
    const float* cw2   = (const float*)d_in[17];
    const float* cb2   = (const float*)d_in[18];
    const float* cg2   = (const float*)d_in[19];
    const float* cbe2  = (const float*)d_in[20];
    const float* cw3   = (const float*)d_in[21];
    const float* cb3   = (const float*)d_in[22];
    const float* cg3   = (const float*)d_in[23];
    const float* cbe3  = (const float*)d_in[24];
    float* out = (float*)d_out;
    float* ws  = (float*)d_ws;
    __hip_bfloat16* I0cl = (__hip_bfloat16*)(ws + OFF_I0CL);
    __hip_bfloat16* wT1b = (__hip_bfloat16*)(ws + OFF_WT1B);

    hipMemsetAsync(ws + OFF_SX,  0,    4192*4, stream);        // SX + MST
    hipMemsetAsync(ws + OFF_BG2, 0,    5120*4, stream);        // BG2 + BG3
    hipMemsetAsync(ws + OFF_WIN, 0xFF, 16000*4, stream);
    hipMemsetAsync(ws + OFF_I0CL, 0, 1485824ull*4, stream);    // bf16 I0cl (incl slack)

    k_t_tile<<<777,256,0,stream>>>(cw2, cw3, w2, cw1, ws+OFF_WT2, ws+OFF_WT3, ws+OFF_W2T, wT1b);
    k_stats_x<<<750,256,0,stream>>>(vf, ws+OFF_SX);
    k_ac1<<<1,64,0,stream>>>(ws+OFF_SX, w1,b1,g1,be1, ws+OFF_AC1);
    k_vfe1<<<6000,256,0,stream>>>(vf, w1, ws+OFF_AC1, ws+OFF_F1);
    k_stats_f1<<<256,256,0,stream>>>(ws+OFF_F1, ws+OFF_MSTP);
    k_red_mst<<<65,64,0,stream>>>(ws+OFF_MSTP, ws+OFF_MST);
    k_ac2<<<128,64,0,stream>>>(ws+OFF_MST, w2,b2,g2,be2, ws+OFF_AC2);
    k_scatter<<<94,256,0,stream>>>(coords, (int*)(ws+OFF_WIN));
    k_I0<<<800,256,0,stream>>>((int*)(ws+OFF_WIN), ws+OFF_F1, ws+OFF_W2T, ws+OFF_AC2, I0cl);
    k_conv1m<<<1760,256,0,stream>>>(I0cl, wT1b, ws+OFF_RAW1);
    k_stats_c1<<<128,256,0,stream>>>(ws+OFF_RAW1, cb1,cg1,cbe1, ws+OFF_ACB1);
    k_fill_I1<<<2288,256,0,stream>>>(ws+OFF_RAW1, ws+OFF_ACB1, cb1, ws+OFF_I1);
    k_bg2<<<16,256,0,stream>>>(ws+OFF_WT2, ws+OFF_ACB1, ws+OFF_BG2);
    k_conv2<<<960,256,0,stream>>>(ws+OFF_I1, ws+OFF_WT2, ws+OFF_RAW2);
    k_stats_c2<<<256,64,0,stream>>>(ws+OFF_RAW2, ws+OFF_BG2, cb2, cg2, cbe2, ws+OFF_ACB2);
    k_fill_I2<<<1512,256,0,stream>>>(ws+OFF_RAW2, ws+OFF_ACB2, cb2, ws+OFF_I2);
    k_bg3<<<32,256,0,stream>>>(ws+OFF_WT3, ws+OFF_ACB2, ws+OFF_BG3);
    k_conv3<<<768,256,0,stream>>>(ws+OFF_I2, ws+OFF_WT3, ws+OFF_RAW3);
    k_stats_c3<<<256,64,0,stream>>>(ws+OFF_RAW3, ws+OFF_BG3, cb3, cg3, cbe3, ws+OFF_AC3);
    k_final<<<1536,256,0,stream>>>(ws+OFF_RAW3, ws+OFF_BG3, cb3, ws+OFF_AC3, out);
}

// Round 12
// 350.930 us; speedup vs baseline: 1.2430x; 1.1046x over previous
//
#include <hip/hip_runtime.h>
#include <hip/hip_bf16.h>

#define EPS 1e-5f

// ---- problem dims ----
#define BB 2
#define NV 12000
#define NP 32
#define CIN 5
#define GD 20
// conv1: active out 10x11x11; conv2 region 5x6x6; conv3 region 3x4x4

typedef __attribute__((ext_vector_type(8))) short bf16x8;
typedef __attribute__((ext_vector_type(4))) float f32x4;

// ---- workspace layout (float offsets) ----
static const size_t OFF_SX   = 0;         // 32   (fully written by k_red_sx)
static const size_t OFF_MST  = 32;        // 4160 (fully written by k_red_mst)
static const size_t OFF_AC1  = 4192;      // 128
static const size_t OFF_AC2  = 4320;      // 256
static const size_t OFF_ACB1 = 4576;      // 384  (A[128],C[128],bg1[128])
static const size_t OFF_ACB2 = 4960;      // 2560 (A[256],C[256],bgn2[256*8])
static const size_t OFF_AC3  = 7520;      // 512
static const size_t OFF_BG2  = 8032;      // 2048   [memset1: 8032..13152]
static const size_t OFF_BG3  = 10080;     // 3072
static const size_t OFF_W2T  = 13152;     // 8192
static const size_t OFF_WIN  = 21344;     // 16000 ints [memset 0xFF]
static const size_t OFF_F1   = 37344;     // 1,536,000
static const size_t OFF_I0CL = 1573344;   // bf16 [b][21][23][24][128ci] (+slack) = 1,485,824 floats (memset 0)
static const size_t OFF_I1   = 3059168;   // 585,728   [b][ci][11][13][16]
static const size_t OFF_I2   = 3644896;   // 387,072   [b][ci][7][9][12]
static const size_t OFF_WT1B = 4031968;   // bf16 [27][128co][128ci] = 221,184 floats
static const size_t OFF_WT2  = 4253152;   // 884,736
static const size_t OFF_WT3  = 5137888;   // 1,769,472
static const size_t OFF_RAW1 = 6907360;   // 4 x 309,760
static const size_t OFF_RAW2 = 8146400;   // 16 x 92,160
static const size_t OFF_RAW3 = 9620960;   // 32 x 24,576
static const size_t OFF_MSTP = 10407392;  // 256 x 4160 partials (fully written)
static const size_t OFF_SXP  = 11472352;  // 20 x 768 partials (fully written rows 0..749)
// end = 11,487,712 floats = 46.0 MB

// ================= VFE stage =================

// moment accumulation, fully atomic-free: butterfly shuffle reduce + per-block partial
__global__ __launch_bounds__(256) void k_stats_x(const float* __restrict__ vf, float* __restrict__ sxp) {
    __shared__ float st[5120];
    __shared__ float sw[4*20];
    int t = threadIdx.x;
    const float4* src = (const float4*)(vf + (size_t)blockIdx.x*5120);
    #pragma unroll
    for (int i=0;i<5;i++) ((float4*)st)[i*256 + t] = src[i*256 + t];
    __syncthreads();
    float vals[20];
    #pragma unroll
    for (int i=0;i<20;i++) vals[i]=0.f;
    const float* base = st + t*20;
    #pragma unroll
    for (int p=0;p<4;p++){
        const float* v = base + p*5;
        int k=5;
        #pragma unroll
        for (int c=0;c<5;c++){
            vals[c]+=v[c];
            #pragma unroll
            for(int c2=c;c2<5;c2++){ vals[k++]+=v[c]*v[c2]; }
        }
    }
    #pragma unroll
    for (int off=32; off>0; off>>=1){
        #pragma unroll
        for (int i=0;i<20;i++) vals[i] += __shfl_down(vals[i], off);
    }
    int wave = t>>6, lane = t&63;
    if (lane==0){
        #pragma unroll
        for (int i=0;i<20;i++) sw[wave*20+i]=vals[i];
    }
    __syncthreads();
    if (t<20){
        float s = sw[t]+sw[20+t]+sw[40+t]+sw[60+t];
        sxp[(size_t)t*768 + blockIdx.x] = s;
    }
}

// reduce 750 per-block partials -> SX[20]
__global__ __launch_bounds__(256) void k_red_sx(const float* __restrict__ sxp, float* __restrict__ out){
    int c = blockIdx.x;
    int t = threadIdx.x;
    float s = 0.f;
    for (int b=t; b<750; b+=256) s += sxp[(size_t)c*768 + b];
    __shared__ float sh[256];
    sh[t]=s; __syncthreads();
    for (int st2=128; st2>0; st2>>=1){ if (t<st2) sh[t]+=sh[t+st2]; __syncthreads(); }
    if (t==0) out[c]=sh[0];
}

__global__ void k_ac1(const float* __restrict__ stats, const float* __restrict__ w1,
                      const float* __restrict__ b1, const float* __restrict__ g1,
                      const float* __restrict__ be1, float* __restrict__ AC1){
    int o = threadIdx.x; if (o>=64) return;
    const float N = (float)(BB*NV*NP);
    float w[5];
    #pragma unroll
    for(int c=0;c<5;c++) w[c]=w1[o*5+c];
    float b=b1[o];
    float wd=0;
    #pragma unroll
    for(int c=0;c<5;c++) wd += w[c]*stats[c];
    float m = wd/N + b;
    float q=0; int kk=5;
    for(int c=0;c<5;c++) for(int c2=c;c2<5;c2++){ float s=stats[kk++]; q += (c==c2?1.f:2.f)*w[c]*w[c2]*s; }
    q = q/N + 2.f*b*wd/N + b*b;
    float var = q - m*m;
    float A = g1[o]*rsqrtf(var + EPS);
    AC1[o] = A;
    AC1[64+o] = be1[o] + (b - m)*A;
}

__global__ __launch_bounds__(256) void k_vfe1(const float* __restrict__ vf, const float* __restrict__ w1,
                                              const float* __restrict__ AC1, float* __restrict__ f1){
    int wave = threadIdx.x >> 6;
    int lane = threadIdx.x & 63;
    int v = blockIdx.x*4 + wave;
    if (v >= BB*NV) return;
    float w[5];
    #pragma unroll
    for (int c=0;c<5;c++) w[c] = w1[lane*5+c];
    float A = AC1[lane], Cc = AC1[64+lane];
    const float* x = vf + (size_t)v*(NP*CIN);
    float mx = -1e30f;
    #pragma unroll
    for (int pc = 0; pc < 8; pc++) {
        float xx[20];
        const float4* x4 = (const float4*)(x + pc*20);
        #pragma unroll
        for (int i=0;i<5;i++){ float4 t = x4[i]; xx[4*i]=t.x; xx[4*i+1]=t.y; xx[4*i+2]=t.z; xx[4*i+3]=t.w; }
        #pragma unroll
        for (int j=0;j<4;j++){
            float y = xx[j*5]*w[0]+xx[j*5+1]*w[1]+xx[j*5+2]*w[2]+xx[j*5+3]*w[3]+xx[j*5+4]*w[4];
            mx = fmaxf(mx, y*A + Cc);
        }
    }
    f1[(size_t)v*64 + lane] = fmaxf(mx, 0.f);
}

// atomic-free: each block writes its 4160-float accumulator to a private partial slice
__global__ __launch_bounds__(256) void k_stats_f1(const float* __restrict__ f1, float* __restrict__ Mpart){
    __shared__ float tile[16][64];
    __shared__ float ssum[64];
    int t = threadIdx.x;
    if (t < 64) ssum[t]=0.f;
    float acc[4][4];
    #pragma unroll
    for(int i=0;i<4;i++)
        #pragma unroll
        for(int j=0;j<4;j++) acc[i][j]=0.f;
    int i4 = (t>>4)*4, j4 = (t&15)*4;
    const int NT = (BB*NV)/16; // 1500
    for (int tl = blockIdx.x; tl < NT; tl += gridDim.x) {
        __syncthreads();
        for (int i = t; i < 16*64; i += 256) tile[i>>6][i&63] = f1[(size_t)tl*1024 + i];
        __syncthreads();
        #pragma unroll
        for (int r=0;r<16;r++){
            float a[4], bb[4];
            #pragma unroll
            for (int u=0;u<4;u++) a[u]=tile[r][i4+u];
            #pragma unroll
            for (int u=0;u<4;u++) bb[u]=tile[r][j4+u];
            #pragma unroll
            for (int u=0;u<4;u++)
                #pragma unroll
                for (int q=0;q<4;q++) acc[u][q] += a[u]*bb[q];
        }
        if (t < 64) {
            float s=0;
            #pragma unroll
            for(int r=0;r<16;r++) s+=tile[r][t];
            ssum[t]+=s;
        }
    }
    float* mp = Mpart + (size_t)blockIdx.x*4160;
    #pragma unroll
    for(int i=0;i<4;i++)
        #pragma unroll
        for(int j=0;j<4;j++) mp[(size_t)(i4+i)*64 + (j4+j)] = acc[i][j];
    __syncthreads();
    if (t<64) mp[4096 + t] = ssum[t];
}

// reduce 256 partial slices -> Mst[4160]
__global__ __launch_bounds__(64) void k_red_mst(const float* __restrict__ Mpart, float* __restrict__ Mst){
    int e = blockIdx.x*64 + threadIdx.x;
    if (e >= 4160) return;
    float s = 0.f;
    #pragma unroll 8
    for (int p=0;p<256;p++) s += Mpart[(size_t)p*4160 + e];
    Mst[e] = s;
}

// parallel ac2: one block per o (128 blocks x 64 lanes)
__global__ __launch_bounds__(64) void k_ac2(const float* __restrict__ Mst, const float* __restrict__ w2,
                                            const float* __restrict__ b2, const float* __restrict__ g2,
                                            const float* __restrict__ be2, float* __restrict__ AC2){
    int o = blockIdx.x;
    int j = threadIdx.x;
    const float N = (float)(BB*NV);
    const float* M = Mst; const float* sv = Mst+4096;
    const float* wrow = w2 + o*64;
    float wj = wrow[j];
    float sj = 0.f;
    #pragma unroll 8
    for (int c=0;c<64;c++) sj += wrow[c]*M[c*64+j];
    float q = wj*sj;
    float wdp = wj*sv[j];
    #pragma unroll
    for (int off=32; off>0; off>>=1){ q += __shfl_down(q,off); wdp += __shfl_down(wdp,off); }
    if (j==0){
        float b = b2[o];
        float m = wdp/N + b;
        float qq = q/N + 2.f*b*wdp/N + b*b;
        float var = qq - m*m;
        float A = g2[o]*rsqrtf(var+EPS);
        AC2[o]=A; AC2[128+o]= be2[o] + (b-m)*A;
    }
}

// ================= scatter =================

__global__ void k_scatter(const int* __restrict__ coords, int* __restrict__ winner){
    int i = blockIdx.x*blockDim.x+threadIdx.x;
    if (i >= BB*NV) return;
    int b = i / NV, n = i % NV;
    int d = coords[(size_t)i*3], h = coords[(size_t)i*3+1], w = coords[(size_t)i*3+2];
    if (d<0||d>=GD||h<0||h>=GD||w<0||w>=GD) return;
    atomicMax(&winner[b*8000 + d*400 + h*20 + w], n);
}

// FUSED vfe2 + scatter-fill into channels-last bf16 I0cl[b][21][23][24][128].
__global__ __launch_bounds__(256) void k_I0(const int* __restrict__ winner, const float* __restrict__ f1,
                                            const float* __restrict__ w2T, const float* __restrict__ AC2,
                                            __hip_bfloat16* __restrict__ I0cl){
    int blk = blockIdx.x;
    int b = blk / 400; int dh = blk % 400;
    int d = dh / 20, h = dh % 20;
    __shared__ int win[20];
    __shared__ float f1sh[20][64];
    __shared__ float sh[20*128];   // [w][ci]
    int t = threadIdx.x;
    if (t < 20) win[t] = winner[b*8000 + dh*20 + t];
    __syncthreads();
    for (int idx = t; idx < 1280; idx += 256){
        int cell = idx >> 6, c = idx & 63;
        int n = win[cell];
        f1sh[cell][c] = (n>=0) ? f1[((size_t)(b*NV+n))*64 + c] : 0.f;
    }
    __syncthreads();
    int o = t & 127;
    int half = t >> 7;
    float A = AC2[o], C = AC2[128+o];
    for (int p=0;p<10;p++){
        int cell = p*2 + half;
        float acc = 0.f;
        if (win[cell] >= 0){
            #pragma unroll
            for (int c=0;c<64;c++) acc += f1sh[cell][c]*w2T[c*128+o];
            acc = fmaxf(acc*A + C, 0.f);
        }
        sh[cell*128 + o] = acc;
    }
    __syncthreads();
    __hip_bfloat16* outp = I0cl + (((size_t)(b*21 + d+1)*23 + h+1)*24 + 1)*128;
    for (int idx = t; idx < 2560; idx += 256) outp[idx] = __float2bfloat16(sh[idx]);
}

// ================= merged weight prep =================
// blocks 0..215: wT2 tiles; 216..647: wT3 tiles; 648: w2T; 649..776: wT1b (bf16 pack, co = blk-649)
__global__ __launch_bounds__(256) void k_t_tile(const float* __restrict__ cw2, const float* __restrict__ cw3,
                                                const float* __restrict__ w2, const float* __restrict__ cw1,
                                                float* __restrict__ wT2, float* __restrict__ wT3,
                                                float* __restrict__ w2T, __hip_bfloat16* __restrict__ wT1b){
    int blk = blockIdx.x;
    if (blk >= 649){
        int co = blk - 649;
        __shared__ float tlw[3456];
        int t = threadIdx.x;
        for (int j=t; j<3456; j+=256) tlw[j] = cw1[(size_t)co*3456 + j];   // j = ci*27+tap
        __syncthreads();
        for (int idx=t; idx<3456; idx+=256){
            int tap = idx >> 7, ci = idx & 127;
            wT1b[((size_t)(tap*128 + co) << 7) + ci] = __float2bfloat16(tlw[ci*27 + tap]);
        }
        return;
    }
    if (blk == 648){
        for (int i=threadIdx.x; i<8192; i+=256){ int o=i>>6, c=i&63; w2T[c*128+o]=w2[i]; }
        return;
    }
    const float* src; float* dst; int CO, R;
    if (blk < 216){ src=cw2; dst=wT2; CO=256; R=3456; }
    else { blk-=216; src=cw3; dst=wT3; CO=256; R=6912; }
    int nrt = R/64;
    int rt = blk % nrt, ct = blk / nrt;
    int r0 = rt*64, c0 = ct*64;
    __shared__ float tl[64][65];
    int tj = threadIdx.x & 63;
    int ti0 = threadIdx.x >> 6;
    #pragma unroll
    for (int k=0;k<16;k++){
        int i = ti0 + k*4;
        tl[i][tj] = src[(size_t)(c0+i)*R + r0 + tj];
    }
    __syncthreads();
    #pragma unroll
    for (int k=0;k<16;k++){
        int j = ti0 + k*4;
        dst[(size_t)(r0+j)*CO + c0 + tj] = tl[tj][j];
    }
}

// ================= conv1 via MFMA (bf16 implicit GEMM) =================
// grid 1760 = ((b*10+od)*11+oh)*8 + coq ; 4 waves = kq (K-slices of 32 ci); each wave 27 MFMA.
__global__ __launch_bounds__(256) void k_conv1m(const __hip_bfloat16* __restrict__ I0cl,
                                                const __hip_bfloat16* __restrict__ wT1b,
                                                float* __restrict__ raw1){
    int blk = blockIdx.x;
    int coq = blk & 7; blk >>= 3;
    int oh = blk % 11; blk /= 11;
    int od = blk % 10; int b = blk / 10;
    int kq = threadIdx.x >> 6, lane = threadIdx.x & 63;
    int col = lane & 15, quad = lane >> 4;
    int co0 = coq*16;
    int ci_base = kq*32 + quad*8;
    f32x4 acc = {0.f,0.f,0.f,0.f};
    const __hip_bfloat16* Bb = I0cl + (size_t)b*21*23*24*128 + (2*col)*128 + ci_base;
    const __hip_bfloat16* Ab = wT1b + (size_t)(co0 + col)*128 + ci_base;
    #pragma unroll 3
    for (int tap=0; tap<27; tap++){
        int kd = tap/9, kh = (tap/3)%3, kw = tap%3;
        int d = 2*od + kd, h = 2*oh + kh;     // padded indices
        const __hip_bfloat16* bp = Bb + ((size_t)(d*23 + h)*24 + kw)*128;
        const __hip_bfloat16* ap = Ab + (size_t)tap*16384;
        bf16x8 a0 = *(const bf16x8*)ap;
        bf16x8 b0 = *(const bf16x8*)bp;
        acc = __builtin_amdgcn_mfma_f32_16x16x32_bf16(a0, b0, acc, 0, 0, 0);
    }
    if (col < 11){
        #pragma unroll
        for (int r=0;r<4;r++){
            int co = co0 + quad*4 + r;
            raw1[(size_t)kq*309760 + (((size_t)(b*128+co)*10 + od)*11 + oh)*11 + col] = acc[r];
        }
    }
}

// stats for conv1 (zero background), sums 4 K-split buffers
__global__ __launch_bounds__(256) void k_stats_c1(const float* __restrict__ raw1, const float* __restrict__ cb,
                                                  const float* __restrict__ cg, const float* __restrict__ cbe,
                                                  float* __restrict__ ACb1){
    int co = blockIdx.x;
    float s=0, ss=0;
    for (int b=0;b<2;b++){
        size_t base = ((size_t)(b*128+co))*1210;
        for (int i=threadIdx.x; i<1210; i+=256){
            float v = raw1[base+i] + raw1[309760+base+i] + raw1[2*309760+base+i] + raw1[3*309760+base+i];
            s+=v; ss+=v*v;
        }
    }
    __shared__ float sh1[256], sh2[256];
    sh1[threadIdx.x]=s; sh2[threadIdx.x]=ss; __syncthreads();
    for (int st=128; st>0; st>>=1){
        if (threadIdx.x<st){ sh1[threadIdx.x]+=sh1[threadIdx.x+st]; sh2[threadIdx.x]+=sh2[threadIdx.x+st]; }
        __syncthreads();
    }
    if (threadIdx.x==0){
        float bias = cb[co];
        const float N = 81920.f;   // 2*10*64*64
        float sum_y = sh1[0] + N*bias;
        float ssq_y = sh2[0] + 2.f*bias*sh1[0] + N*bias*bias;
        float m = sum_y/N;
        float var = ssq_y/N - m*m;
        float A = cg[co]*rsqrtf(var+EPS);
        float C = cbe[co] - m*A;
        ACb1[co]=A; ACb1[128+co]=C;
        ACb1[256+co]=fmaxf(bias*A + C, 0.f);  // bg1
    }
}

// I1p[b][ci][11][13][16]
__global__ void k_fill_I1(const float* __restrict__ raw1, const float* __restrict__ ACb1,
                          const float* __restrict__ cb, float* __restrict__ I1p){
    int i = blockIdx.x*blockDim.x + threadIdx.x;   // grid exactly 585,728
    int wpad = i % 16; int r = i / 16;
    int hpad = r % 13; r /= 13;
    int dpad = r % 11; r /= 11;
    int ci = r % 128; int b = r / 128;
    float val;
    if (dpad==0 || hpad==0 || wpad==0 || wpad>12) val = 0.f;
    else {
        int d = dpad-1, h = hpad-1, w = wpad-1;
        if (h < 11 && w < 11){
            size_t idx = (((size_t)(b*128+ci)*10 + d)*11 + h)*11 + w;
            float raw = raw1[idx] + raw1[309760+idx] + raw1[2*309760+idx] + raw1[3*309760+idx];
            val = fmaxf((raw + cb[ci])*ACb1[ci] + ACb1[128+ci], 0.f);
        } else val = ACb1[256+ci];
    }
    I1p[i] = val;
}

// conv2 background class constants: bgraw2[o][8]; coalesced via wT2
__global__ __launch_bounds__(256) void k_bg2(const float* __restrict__ wT2, const float* __restrict__ ACb1,
                                             float* __restrict__ bgraw2){
    int o = threadIdx.x;
    int ci0 = blockIdx.x*8;
    float acc[8];
    #pragma unroll
    for (int c=0;c<8;c++) acc[c]=0.f;
    for (int ci=ci0; ci<ci0+8; ci++){
        float w[27];
        const float* wp = wT2 + (size_t)ci*27*256 + o;
        #pragma unroll
        for (int t=0;t<27;t++) w[t] = wp[t*256];
        float bg = ACb1[256+ci];
        float sw0[9], sw1[9];
        #pragma unroll
        for (int t9=0;t9<9;t9++){ sw1[t9]=w[3*t9+1]+w[3*t9+2]; sw0[t9]=w[3*t9]+sw1[t9]; }
        #pragma unroll
        for (int cls=0; cls<8; cls++){
            const int d0=(cls>>2)&1, h0=(cls>>1)&1, w0=cls&1;
            float ws=0.f;
            #pragma unroll
            for (int kd=0;kd<3;kd++){
                if (d0 && kd==0) continue;
                #pragma unroll
                for (int kh=0;kh<3;kh++){
                    if (h0 && kh==0) continue;
                    ws += w0 ? sw1[kd*3+kh] : sw0[kd*3+kh];
                }
            }
            acc[cls] += bg*ws;
        }
    }
    #pragma unroll
    for (int cls=0;cls<8;cls++) atomicAdd(&bgraw2[o*8+cls], acc[cls]);
}

// conv2: grid 960 = ((b*5+od)*6+oh)*16+ciq ; 256 thr = 4 waves x 2 ci; LDS reduce -> store buf[ciq]
__global__ __launch_bounds__(256) void k_conv2(const float* __restrict__ I1p, const float* __restrict__ wT2,
                                               float* __restrict__ raw2){
    int blk = blockIdx.x;
    int ciq = blk & 15; blk >>= 4;
    int oh = blk % 6; blk /= 6;
    int od = blk % 5; int b = blk / 5;
    int wave = threadIdx.x >> 6, lane = threadIdx.x & 63;
    float acc[4][6];
    #pragma unroll
    for (int q=0;q<4;q++)
        #pragma unroll
        for (int i=0;i<6;i++) acc[q][i]=0.f;
    int ci0 = ciq*8 + wave*2;
    for (int ci = ci0; ci < ci0+2; ci++){
        const float* base = I1p + ((size_t)(b*128+ci)*11 + 2*od)*208 + (2*oh)*16;
        const float* wp0 = wT2 + (size_t)ci*27*256 + lane;
        #pragma unroll
        for (int kd=0;kd<3;kd++){
            #pragma unroll
            for (int kh=0;kh<3;kh++){
                float row[16];
                const float4* rp = (const float4*)(base + kd*208 + kh*16);
                #pragma unroll
                for (int i=0;i<4;i++){ float4 t=rp[i]; row[4*i]=t.x; row[4*i+1]=t.y; row[4*i+2]=t.z; row[4*i+3]=t.w; }
                const float* wp = wp0 + (kd*3+kh)*3*256;
                #pragma unroll
                for (int kw=0;kw<3;kw++){
                    float w0=wp[kw*256], w1=wp[kw*256+64], w2v=wp[kw*256+128], w3=wp[kw*256+192];
                    #pragma unroll
                    for (int ow=0;ow<6;ow++){
                        float x = row[2*ow+kw];
                        acc[0][ow]+=x*w0; acc[1][ow]+=x*w1; acc[2][ow]+=x*w2v; acc[3][ow]+=x*w3;
                    }
                }
            }
        }
    }
    __shared__ float red[4*1540];
    #pragma unroll
    for (int q=0;q<4;q++)
        #pragma unroll
        for (int ow=0;ow<6;ow++) red[wave*1540 + lane*24 + q*6 + ow] = acc[q][ow];
    __syncthreads();
    float* rb = raw2 + (size_t)ciq*92160;
    for (int idx = threadIdx.x; idx < 1536; idx += 256){
        int lane2 = idx/24, j = idx%24;
        float s = red[0*1540 + lane2*24 + j] + red[1*1540 + lane2*24 + j]
                + red[2*1540 + lane2*24 + j] + red[3*1540 + lane2*24 + j];
        int q = j/6, ow = j%6;
        int co = q*64 + lane2;
        rb[(((size_t)(b*256+co)*5 + od)*6 + oh)*6 + ow] = s;
    }
}

// conv2 BN stats from raw interior (16 buffers) + analytic background class counts
__global__ __launch_bounds__(64) void k_stats_c2(const float* __restrict__ raw2, const float* __restrict__ bgraw2,
                                                 const float* __restrict__ cb2, const float* __restrict__ cg2,
                                                 const float* __restrict__ cbe2, float* __restrict__ ACb2){
    int o = blockIdx.x;
    int lane = threadIdx.x;
    float s=0.f, ss=0.f;
    for (int idx=lane; idx<360; idx+=64){
        int b = idx/180; int p = idx%180;
        int d = p/36; int rem = p%36; int h = rem/6; int w = rem%6;
        size_t base = (((size_t)(b*256+o)*5 + d)*6 + h)*6 + w;
        float v = 0.f;
        #pragma unroll
        for (int q=0;q<16;q++) v += raw2[q*92160+base];
        s += v; ss += v*v;
    }
    #pragma unroll
    for (int off=32; off>0; off>>=1){ s += __shfl_down(s,off); ss += __shfl_down(ss,off); }
    if (lane==0){
        const int n2[8] = {3744,104,104,0,936,26,26,0};   // per batch; x2 batches
        float bgv[8];
        #pragma unroll
        for (int c=0;c<8;c++){ bgv[c]=bgraw2[o*8+c]; s += 2.f*n2[c]*bgv[c]; ss += 2.f*n2[c]*bgv[c]*bgv[c]; }
        const float N = 10240.f;
        float b = cb2[o];
        float sum_y = s + N*b;
        float ssq_y = ss + 2.f*b*s + N*b*b;
        float m = sum_y/N;
        float var = ssq_y/N - m*m;
        float A = cg2[o]*rsqrtf(var+EPS); float C = cbe2[o] - m*A;
        ACb2[o]=A; ACb2[256+o]=C;
        for (int c=0;c<8;c++) ACb2[512+o*8+c] = fmaxf((bgv[c]+b)*A + C, 0.f);
    }
}

// I2p[b][ci][7][9][12]
__global__ void k_fill_I2(const float* __restrict__ raw2, const float* __restrict__ ACb2,
                          const float* __restrict__ cb2, float* __restrict__ I2p){
    int i = blockIdx.x*blockDim.x + threadIdx.x;   // grid exactly 387,072
    int wpad = i % 12; int r = i / 12;
    int hpad = r % 9; r /= 9;
    int dpad = r % 7; r /= 7;
    int ci = r % 256; int b = r / 256;
    float val;
    if (dpad==0 || dpad==6 || hpad==0 || wpad==0 || wpad>8) val = 0.f;
    else {
        int d = dpad-1, h = hpad-1, w = wpad-1;
        if (h<6 && w<6){
            size_t idx = (((size_t)(b*256+ci)*5 + d)*6 + h)*6 + w;
            float raw = 0.f;
            #pragma unroll
            for (int q=0;q<16;q++) raw += raw2[q*92160+idx];
            val = fmaxf((raw + cb2[ci])*ACb2[ci] + ACb2[256+ci], 0.f);
        } else {
            int cls = ((d==0)?4:0) | ((h==0)?2:0) | ((w==0)?1:0);
            val = ACb2[512 + ci*8 + cls];
        }
    }
    I2p[i] = val;
}

// conv3 background classes: bgraw3[o][12]; coalesced via wT3
__global__ __launch_bounds__(256) void k_bg3(const float* __restrict__ wT3, const float* __restrict__ ACb2,
                                             float* __restrict__ bgraw3){
    int o = threadIdx.x;
    int ci0 = blockIdx.x*8;
    float acc[12];
    #pragma unroll
    for (int c=0;c<12;c++) acc[c]=0.f;
    for (int ci=ci0; ci<ci0+8; ci++){
        float w[27];
        const float* wp = wT3 + (size_t)ci*27*256 + o;
        #pragma unroll
        for (int t=0;t<27;t++) w[t] = wp[t*256];
        const float* bg = ACb2 + 512 + ci*8;
        float bgv[8];
        #pragma unroll
        for (int q=0;q<8;q++) bgv[q]=bg[q];
        #pragma unroll
        for (int c=0;c<12;c++){
            const int odc = c>>2; const int h0 = (c>>1)&1; const int w0 = c&1;
            float sum = 0.f;
            #pragma unroll
            for (int kd=0;kd<3;kd++){
                const int d = 2*odc-1+kd; if (d<0||d>=5) continue;
                const int db = (d==0)?4:0;
                #pragma unroll
                for (int kh=0;kh<3;kh++){
                    if (h0 && kh==0) continue;
                    const int hb = (h0 && kh==1)?2:0;
                    #pragma unroll
                    for (int kw=0;kw<3;kw++){
                        if (w0 && kw==0) continue;
                        const int wb = (w0 && kw==1)?1:0;
                        sum += bgv[db|hb|wb]*w[(kd*3+kh)*3+kw];
                    }
                }
            }
            acc[c] += sum;
        }
    }
    #pragma unroll
    for (int c=0;c<12;c++) atomicAdd(&bgraw3[o*12+c], acc[c]);
}

// conv3: grid 768 = ((b*3+od)*4+oh)*32+ciq ; 256 thr = 4 waves x 2 ci; LDS reduce -> store buf[ciq]
__global__ __launch_bounds__(256) void k_conv3(const float* __restrict__ I2p, const float* __restrict__ wT3,
                                               float* __restrict__ raw3){
    int blk = blockIdx.x;
    int ciq = blk & 31; blk >>= 5;
    int oh = blk % 4; blk /= 4;
    int od = blk % 3; int b = blk / 3;
    int wave = threadIdx.x >> 6, lane = threadIdx.x & 63;
    float acc[4][4];
    #pragma unroll
    for (int q=0;q<4;q++)
        #pragma unroll
        for (int i=0;i<4;i++) acc[q][i]=0.f;
    int ci0 = ciq*8 + wave*2;
    for (int ci = ci0; ci < ci0+2; ci++){
        const float* base = I2p + ((size_t)(b*256+ci)*7 + 2*od)*108 + (2*oh)*12;
        const float* wp0 = wT3 + (size_t)ci*27*256 + lane;
        #pragma unroll
        for (int kd=0;kd<3;kd++){
            #pragma unroll
            for (int kh=0;kh<3;kh++){
                float row[12];
                const float4* rp = (const float4*)(base + kd*108 + kh*12);
                #pragma unroll
                for (int i=0;i<3;i++){ float4 t=rp[i]; row[4*i]=t.x; row[4*i+1]=t.y; row[4*i+2]=t.z; row[4*i+3]=t.w; }
                const float* wp = wp0 + (kd*3+kh)*3*256;
                #pragma unroll
                for (int kw=0;kw<3;kw++){
                    float w0=wp[kw*256], w1=wp[kw*256+64], w2v=wp[kw*256+128], w3=wp[kw*256+192];
                    #pragma unroll
                    for (int ow=0;ow<4;ow++){
                        float x = row[2*ow+kw];
                        acc[0][ow]+=x*w0; acc[1][ow]+=x*w1; acc[2][ow]+=x*w2v; acc[3][ow]+=x*w3;
                    }
                }
            }
        }
    }
    __shared__ float red[4*1028];
    #pragma unroll
    for (int q=0;q<4;q++)
        #pragma unroll
        for (int ow=0;ow<4;ow++) red[wave*1028 + lane*16 + q*4 + ow] = acc[q][ow];
    __syncthreads();
    float* rb = raw3 + (size_t)ciq*24576;
    for (int idx = threadIdx.x; idx < 1024; idx += 256){
        int lane2 = idx/16, j = idx%16;
        float s = red[0*1028 + lane2*16 + j] + red[1*1028 + lane2*16 + j]
                + red[2*1028 + lane2*16 + j] + red[3*1028 + lane2*16 + j];
        int q = j/4, ow = j%4;
        int co = q*64 + lane2;
        rb[(((size_t)(b*256+co)*3 + od)*4 + oh)*4 + ow] = s;
    }
}

// conv3 BN stats from raw interior (32 buffers) + analytic class counts
__global__ __launch_bounds__(64) void k_stats_c3(const float* __restrict__ raw3, const float* __restrict__ bgraw3,
                                                 const float* __restrict__ cb3, const float* __restrict__ cg3,
                                                 const float* __restrict__ cbe3, float* __restrict__ AC3){
    int o = blockIdx.x;
    int lane = threadIdx.x;
    float s=0.f, ss=0.f;
    for (int idx=lane; idx<96; idx+=64){
        int b = idx/48; int p = idx%48;
        int d = p/16; int rem = p%16; int h = rem/4; int w = rem%4;
        size_t base = (((size_t)(b*256+o)*3 + d)*4 + h)*4 + w;
        float v = 0.f;
        #pragma unroll
        for (int q=0;q<32;q++) v += raw3[q*24576+base];
        s += v; ss += v*v;
    }
    #pragma unroll
    for (int off=32; off>0; off>>=1){ s += __shfl_down(s,off); ss += __shfl_down(ss,off); }
    if (lane==0){
        const int n3hw[4] = {216,12,12,0};   // per (b,od)
        for (int c=0;c<12;c++){
            float bg = bgraw3[o*12+c];
            float n = 2.f*n3hw[c&3];
            s += n*bg; ss += n*bg*bg;
        }
        const float N = 1536.f;
        float b = cb3[o];
        float sum_y = s + N*b;
        float ssq_y = ss + 2.f*b*s + N*b*b;
        float m = sum_y/N;
        float var = ssq_y/N - m*m;
        float A = cg3[o]*rsqrtf(var+EPS);
        AC3[o]=A; AC3[256+o]=cbe3[o] - m*A;
    }
}

// final output directly from raw3/bg3
__global__ void k_final(const float* __restrict__ raw3, const float* __restrict__ bgraw3,
                        const float* __restrict__ cb3, const float* __restrict__ AC3,
                        float* __restrict__ out){
    int i = blockIdx.x*blockDim.x + threadIdx.x;
    if (i >= 2*256*3*16*16) return;
    int ow = i % 16; int r = i / 16;
    int oh = r % 16; r /= 16;
    int od = r % 3; r /= 3;
    int o = r % 256; int b = r / 256;
    float v;
    if (oh<4 && ow<4){
        size_t base = (((size_t)(b*256+o)*3 + od)*4 + oh)*4 + ow;
        v = 0.f;
        #pragma unroll
        for (int q=0;q<32;q++) v += raw3[q*24576+base];
    } else {
        v = bgraw3[o*12 + od*4 + ((oh==0)?2:0) + ((ow==0)?1:0)];
    }
    out[i] = fmaxf((v + cb3[o])*AC3[o] + AC3[256+o], 0.f);
}

// ================= launch =================

extern "C" void kernel_launch(void* const* d_in, const int* in_sizes, int n_in,
                              void* d_out, int out_size, void* d_ws, size_t ws_size,
                              hipStream_t stream) {
    const float* vf    = (const float*)d_in[0];
    const int*   coords= (const int*)d_in[1];
    const float* w1    = (const float*)d_in[5];
    const float* b1    = (const float*)d_in[6];
    const float* g1    = (const float*)d_in[7];
    const float* be1   = (const float*)d_in[8];
    const float* w2    = (const float*)d_in[9];
    const float* b2    = (const float*)d_in[10];
    const float* g2    = (const float*)d_in[11];
    const float* be2   = (const float*)d_in[12];
    const float* cw1   = (const float*)d_in[13];
    const float* cb1   = (const float*)d_in[14];
    const float* cg1   = (const float*)d_in[15];
    const float* cbe1  = (const float*)d_in[16];
    const float* cw2   = (const float*)d_in[17];
    const float* cb2   = (const float*)d_in[18];
    const float* cg2   = (const float*)d_in[19];
    const float* cbe2  = (const float*)d_in[20];
    const float* cw3   = (const float*)d_in[21];
    const float* cb3   = (const float*)d_in[22];
    const float* cg3   = (const float*)d_in[23];
    const float* cbe3  = (const float*)d_in[24];
    float* out = (float*)d_out;
    float* ws  = (float*)d_ws;
    __hip_bfloat16* I0cl = (__hip_bfloat16*)(ws + OFF_I0CL);
    __hip_bfloat16* wT1b = (__hip_bfloat16*)(ws + OFF_WT1B);

    hipMemsetAsync(ws + OFF_BG2, 0,    5120*4, stream);        // BG2 + BG3
    hipMemsetAsync(ws + OFF_WIN, 0xFF, 16000*4, stream);
    hipMemsetAsync(ws + OFF_I0CL, 0, 1485824ull*4, stream);    // bf16 I0cl (incl slack)

    k_t_tile<<<777,256,0,stream>>>(cw2, cw3, w2, cw1, ws+OFF_WT2, ws+OFF_WT3, ws+OFF_W2T, wT1b);
    k_stats_x<<<750,256,0,stream>>>(vf, ws+OFF_SXP);
    k_red_sx<<<20,256,0,stream>>>(ws+OFF_SXP, ws+OFF_SX);
    k_ac1<<<1,64,0,stream>>>(ws+OFF_SX, w1,b1,g1,be1, ws+OFF_AC1);
    k_vfe1<<<6000,256,0,stream>>>(vf, w1, ws+OFF_AC1, ws+OFF_F1);
    k_stats_f1<<<256,256,0,stream>>>(ws+OFF_F1, ws+OFF_MSTP);
    k_red_mst<<<65,64,0,stream>>>(ws+OFF_MSTP, ws+OFF_MST);
    k_ac2<<<128,64,0,stream>>>(ws+OFF_MST, w2,b2,g2,be2, ws+OFF_AC2);
    k_scatter<<<94,256,0,stream>>>(coords, (int*)(ws+OFF_WIN));
    k_I0<<<800,256,0,stream>>>((int*)(ws+OFF_WIN), ws+OFF_F1, ws+OFF_W2T, ws+OFF_AC2, I0cl);
    k_conv1m<<<1760,256,0,stream>>>(I0cl, wT1b, ws+OFF_RAW1);
    k_stats_c1<<<128,256,0,stream>>>(ws+OFF_RAW1, cb1,cg1,cbe1, ws+OFF_ACB1);
    k_fill_I1<<<2288,256,0,stream>>>(ws+OFF_RAW1, ws+OFF_ACB1, cb1, ws+OFF_I1);
    k_bg2<<<16,256,0,stream>>>(ws+OFF_WT2, ws+OFF_ACB1, ws+OFF_BG2);
    k_conv2<<<960,256,0,stream>>>(ws+OFF_I1, ws+OFF_WT2, ws+OFF_RAW2);
    k_stats_c2<<<256,64,0,stream>>>(ws+OFF_RAW2, ws+OFF_BG2, cb2, cg2, cbe2, ws+OFF_ACB2);
    k_fill_I2<<<1512,256,0,stream>>>(ws+OFF_RAW2, ws+OFF_ACB2, cb2, ws+OFF_I2);
    k_bg3<<<32,256,0,stream>>>(ws+OFF_WT3, ws+OFF_ACB2, ws+OFF_BG3);
    k_conv3<<<768,256,0,stream>>>(ws+OFF_I2, ws+OFF_WT3, ws+OFF_RAW3);
    k_stats_c3<<<256,64,0,stream>>>(ws+OFF_RAW3, ws+OFF_BG3, cb3, cg3, cbe3, ws+OFF_AC3);
    k_final<<<1536,256,0,stream>>>(ws+OFF_RAW3, ws+OFF_BG3, cb3, ws+OFF_AC3, out);
}

// Round 13
// 346.374 us; speedup vs baseline: 1.2593x; 1.0132x over previous
//
#include <hip/hip_runtime.h>
#include <hip/hip_bf16.h>

#define EPS 1e-5f

// ---- problem dims ----
#define BB 2
#define NV 12000
#define NP 32
#define CIN 5
#define GD 20
// conv1: active out 10x11x11; conv2 region 5x6x6; conv3 region 3x4x4

typedef __attribute__((ext_vector_type(8))) short bf16x8;
typedef __attribute__((ext_vector_type(4))) float f32x4;

// ---- workspace layout (float offsets) ----
static const size_t OFF_SX   = 0;         // 32   (fully written by k_red_sx)
static const size_t OFF_MST  = 32;        // 4160 (fully written by k_red_mst)
static const size_t OFF_AC1  = 4192;      // 128
static const size_t OFF_AC2  = 4320;      // 256
static const size_t OFF_ACB1 = 4576;      // 384  (A[128],C[128],bg1[128])
static const size_t OFF_ACB2 = 4960;      // 2560 (A[256],C[256],bgn2[256*8])
static const size_t OFF_AC3  = 7520;      // 512
static const size_t OFF_BG2  = 8032;      // 2048   [memset1: 8032..13152]
static const size_t OFF_BG3  = 10080;     // 3072
static const size_t OFF_W2T  = 13152;     // 8192
static const size_t OFF_WIN  = 21344;     // 16000 ints [memset 0xFF]
static const size_t OFF_F1   = 37344;     // 1,536,000
static const size_t OFF_I0CL = 1573344;   // bf16 [b][21][23][24][128ci] (+slack) = 1,485,824 floats (memset 0)
static const size_t OFF_I1   = 3059168;   // 585,728   [b][ci][11][13][16]
static const size_t OFF_I2   = 3644896;   // 387,072   [b][ci][7][9][12]
static const size_t OFF_WT1B = 4031968;   // bf16 [27][128co][128ci] = 221,184 floats
static const size_t OFF_WT2  = 4253152;   // 884,736
static const size_t OFF_WT3  = 5137888;   // 1,769,472
static const size_t OFF_RAW1 = 6907360;   // 4 x 309,760
static const size_t OFF_RAW2 = 8146400;   // 16 x 92,160
static const size_t OFF_RAW3 = 9620960;   // 32 x 24,576
static const size_t OFF_MSTP = 10407392;  // 256 x 4160 partials (fully written)
static const size_t OFF_SXP  = 11472352;  // 20 x 768 partials (fully written rows 0..749)
// end = 11,487,712 floats = 46.0 MB

// ================= VFE stage =================

// moment accumulation, fully atomic-free: butterfly shuffle reduce + per-block partial
__global__ __launch_bounds__(256) void k_stats_x(const float* __restrict__ vf, float* __restrict__ sxp) {
    __shared__ float st[5120];
    __shared__ float sw[4*20];
    int t = threadIdx.x;
    const float4* src = (const float4*)(vf + (size_t)blockIdx.x*5120);
    #pragma unroll
    for (int i=0;i<5;i++) ((float4*)st)[i*256 + t] = src[i*256 + t];
    __syncthreads();
    float vals[20];
    #pragma unroll
    for (int i=0;i<20;i++) vals[i]=0.f;
    const float* base = st + t*20;
    #pragma unroll
    for (int p=0;p<4;p++){
        const float* v = base + p*5;
        int k=5;
        #pragma unroll
        for (int c=0;c<5;c++){
            vals[c]+=v[c];
            #pragma unroll
            for(int c2=c;c2<5;c2++){ vals[k++]+=v[c]*v[c2]; }
        }
    }
    #pragma unroll
    for (int off=32; off>0; off>>=1){
        #pragma unroll
        for (int i=0;i<20;i++) vals[i] += __shfl_down(vals[i], off);
    }
    int wave = t>>6, lane = t&63;
    if (lane==0){
        #pragma unroll
        for (int i=0;i<20;i++) sw[wave*20+i]=vals[i];
    }
    __syncthreads();
    if (t<20){
        float s = sw[t]+sw[20+t]+sw[40+t]+sw[60+t];
        sxp[(size_t)t*768 + blockIdx.x] = s;
    }
}

// reduce 750 per-block partials -> SX[20]
__global__ __launch_bounds__(256) void k_red_sx(const float* __restrict__ sxp, float* __restrict__ out){
    int c = blockIdx.x;
    int t = threadIdx.x;
    float s = 0.f;
    for (int b=t; b<750; b+=256) s += sxp[(size_t)c*768 + b];
    __shared__ float sh[256];
    sh[t]=s; __syncthreads();
    for (int st2=128; st2>0; st2>>=1){ if (t<st2) sh[t]+=sh[t+st2]; __syncthreads(); }
    if (t==0) out[c]=sh[0];
}

__global__ void k_ac1(const float* __restrict__ stats, const float* __restrict__ w1,
                      const float* __restrict__ b1, const float* __restrict__ g1,
                      const float* __restrict__ be1, float* __restrict__ AC1){
    int o = threadIdx.x; if (o>=64) return;
    const float N = (float)(BB*NV*NP);
    float w[5];
    #pragma unroll
    for(int c=0;c<5;c++) w[c]=w1[o*5+c];
    float b=b1[o];
    float wd=0;
    #pragma unroll
    for(int c=0;c<5;c++) wd += w[c]*stats[c];
    float m = wd/N + b;
    float q=0; int kk=5;
    for(int c=0;c<5;c++) for(int c2=c;c2<5;c2++){ float s=stats[kk++]; q += (c==c2?1.f:2.f)*w[c]*w[c2]*s; }
    q = q/N + 2.f*b*wd/N + b*b;
    float var = q - m*m;
    float A = g1[o]*rsqrtf(var + EPS);
    AC1[o] = A;
    AC1[64+o] = be1[o] + (b - m)*A;
}

__global__ __launch_bounds__(256) void k_vfe1(const float* __restrict__ vf, const float* __restrict__ w1,
                                              const float* __restrict__ AC1, float* __restrict__ f1){
    int wave = threadIdx.x >> 6;
    int lane = threadIdx.x & 63;
    int v = blockIdx.x*4 + wave;
    if (v >= BB*NV) return;
    float w[5];
    #pragma unroll
    for (int c=0;c<5;c++) w[c] = w1[lane*5+c];
    float A = AC1[lane], Cc = AC1[64+lane];
    const float* x = vf + (size_t)v*(NP*CIN);
    float mx = -1e30f;
    #pragma unroll
    for (int pc = 0; pc < 8; pc++) {
        float xx[20];
        const float4* x4 = (const float4*)(x + pc*20);
        #pragma unroll
        for (int i=0;i<5;i++){ float4 t = x4[i]; xx[4*i]=t.x; xx[4*i+1]=t.y; xx[4*i+2]=t.z; xx[4*i+3]=t.w; }
        #pragma unroll
        for (int j=0;j<4;j++){
            float y = xx[j*5]*w[0]+xx[j*5+1]*w[1]+xx[j*5+2]*w[2]+xx[j*5+3]*w[3]+xx[j*5+4]*w[4];
            mx = fmaxf(mx, y*A + Cc);
        }
    }
    f1[(size_t)v*64 + lane] = fmaxf(mx, 0.f);
}

// atomic-free: each block writes its 4160-float accumulator to a private partial slice
__global__ __launch_bounds__(256) void k_stats_f1(const float* __restrict__ f1, float* __restrict__ Mpart){
    __shared__ float tile[16][64];
    __shared__ float ssum[64];
    int t = threadIdx.x;
    if (t < 64) ssum[t]=0.f;
    float acc[4][4];
    #pragma unroll
    for(int i=0;i<4;i++)
        #pragma unroll
        for(int j=0;j<4;j++) acc[i][j]=0.f;
    int i4 = (t>>4)*4, j4 = (t&15)*4;
    const int NT = (BB*NV)/16; // 1500
    for (int tl = blockIdx.x; tl < NT; tl += gridDim.x) {
        __syncthreads();
        for (int i = t; i < 16*64; i += 256) tile[i>>6][i&63] = f1[(size_t)tl*1024 + i];
        __syncthreads();
        #pragma unroll
        for (int r=0;r<16;r++){
            float a[4], bb[4];
            #pragma unroll
            for (int u=0;u<4;u++) a[u]=tile[r][i4+u];
            #pragma unroll
            for (int u=0;u<4;u++) bb[u]=tile[r][j4+u];
            #pragma unroll
            for (int u=0;u<4;u++)
                #pragma unroll
                for (int q=0;q<4;q++) acc[u][q] += a[u]*bb[q];
        }
        if (t < 64) {
            float s=0;
            #pragma unroll
            for(int r=0;r<16;r++) s+=tile[r][t];
            ssum[t]+=s;
        }
    }
    float* mp = Mpart + (size_t)blockIdx.x*4160;
    #pragma unroll
    for(int i=0;i<4;i++)
        #pragma unroll
        for(int j=0;j<4;j++) mp[(size_t)(i4+i)*64 + (j4+j)] = acc[i][j];
    __syncthreads();
    if (t<64) mp[4096 + t] = ssum[t];
}

// reduce 256 partial slices -> Mst[4160]
__global__ __launch_bounds__(64) void k_red_mst(const float* __restrict__ Mpart, float* __restrict__ Mst){
    int e = blockIdx.x*64 + threadIdx.x;
    if (e >= 4160) return;
    float s = 0.f;
    #pragma unroll 8
    for (int p=0;p<256;p++) s += Mpart[(size_t)p*4160 + e];
    Mst[e] = s;
}

// parallel ac2: one block per o (128 blocks x 64 lanes)
__global__ __launch_bounds__(64) void k_ac2(const float* __restrict__ Mst, const float* __restrict__ w2,
                                            const float* __restrict__ b2, const float* __restrict__ g2,
                                            const float* __restrict__ be2, float* __restrict__ AC2){
    int o = blockIdx.x;
    int j = threadIdx.x;
    const float N = (float)(BB*NV);
    const float* M = Mst; const float* sv = Mst+4096;
    const float* wrow = w2 + o*64;
    float wj = wrow[j];
    float sj = 0.f;
    #pragma unroll 8
    for (int c=0;c<64;c++) sj += wrow[c]*M[c*64+j];
    float q = wj*sj;
    float wdp = wj*sv[j];
    #pragma unroll
    for (int off=32; off>0; off>>=1){ q += __shfl_down(q,off); wdp += __shfl_down(wdp,off); }
    if (j==0){
        float b = b2[o];
        float m = wdp/N + b;
        float qq = q/N + 2.f*b*wdp/N + b*b;
        float var = qq - m*m;
        float A = g2[o]*rsqrtf(var+EPS);
        AC2[o]=A; AC2[128+o]= be2[o] + (b-m)*A;
    }
}

// ================= scatter =================

__global__ void k_scatter(const int* __restrict__ coords, int* __restrict__ winner){
    int i = blockIdx.x*blockDim.x+threadIdx.x;
    if (i >= BB*NV) return;
    int b = i / NV, n = i % NV;
    int d = coords[(size_t)i*3], h = coords[(size_t)i*3+1], w = coords[(size_t)i*3+2];
    if (d<0||d>=GD||h<0||h>=GD||w<0||w>=GD) return;
    atomicMax(&winner[b*8000 + d*400 + h*20 + w], n);
}

// FUSED vfe2 + scatter-fill into channels-last bf16 I0cl[b][21][23][24][128].
__global__ __launch_bounds__(256) void k_I0(const int* __restrict__ winner, const float* __restrict__ f1,
                                            const float* __restrict__ w2T, const float* __restrict__ AC2,
                                            __hip_bfloat16* __restrict__ I0cl){
    int blk = blockIdx.x;
    int b = blk / 400; int dh = blk % 400;
    int d = dh / 20, h = dh % 20;
    __shared__ int win[20];
    __shared__ float f1sh[20][64];
    __shared__ float sh[20*128];   // [w][ci]
    int t = threadIdx.x;
    if (t < 20) win[t] = winner[b*8000 + dh*20 + t];
    __syncthreads();
    for (int idx = t; idx < 1280; idx += 256){
        int cell = idx >> 6, c = idx & 63;
        int n = win[cell];
        f1sh[cell][c] = (n>=0) ? f1[((size_t)(b*NV+n))*64 + c] : 0.f;
    }
    __syncthreads();
    int o = t & 127;
    int half = t >> 7;
    float A = AC2[o], C = AC2[128+o];
    for (int p=0;p<10;p++){
        int cell = p*2 + half;
        float acc = 0.f;
        if (win[cell] >= 0){
            #pragma unroll
            for (int c=0;c<64;c++) acc += f1sh[cell][c]*w2T[c*128+o];
            acc = fmaxf(acc*A + C, 0.f);
        }
        sh[cell*128 + o] = acc;
    }
    __syncthreads();
    __hip_bfloat16* outp = I0cl + (((size_t)(b*21 + d+1)*23 + h+1)*24 + 1)*128;
    for (int idx = t; idx < 2560; idx += 256) outp[idx] = __float2bfloat16(sh[idx]);
}

// ================= merged weight prep =================
// blocks 0..215: wT2 tiles; 216..647: wT3 tiles; 648: w2T; 649..776: wT1b (bf16 pack, co = blk-649)
__global__ __launch_bounds__(256) void k_t_tile(const float* __restrict__ cw2, const float* __restrict__ cw3,
                                                const float* __restrict__ w2, const float* __restrict__ cw1,
                                                float* __restrict__ wT2, float* __restrict__ wT3,
                                                float* __restrict__ w2T, __hip_bfloat16* __restrict__ wT1b){
    int blk = blockIdx.x;
    if (blk >= 649){
        int co = blk - 649;
        __shared__ float tlw[3456];
        int t = threadIdx.x;
        for (int j=t; j<3456; j+=256) tlw[j] = cw1[(size_t)co*3456 + j];   // j = ci*27+tap
        __syncthreads();
        for (int idx=t; idx<3456; idx+=256){
            int tap = idx >> 7, ci = idx & 127;
            wT1b[((size_t)(tap*128 + co) << 7) + ci] = __float2bfloat16(tlw[ci*27 + tap]);
        }
        return;
    }
    if (blk == 648){
        for (int i=threadIdx.x; i<8192; i+=256){ int o=i>>6, c=i&63; w2T[c*128+o]=w2[i]; }
        return;
    }
    const float* src; float* dst; int CO, R;
    if (blk < 216){ src=cw2; dst=wT2; CO=256; R=3456; }
    else { blk-=216; src=cw3; dst=wT3; CO=256; R=6912; }
    int nrt = R/64;
    int rt = blk % nrt, ct = blk / nrt;
    int r0 = rt*64, c0 = ct*64;
    __shared__ float tl[64][65];
    int tj = threadIdx.x & 63;
    int ti0 = threadIdx.x >> 6;
    #pragma unroll
    for (int k=0;k<16;k++){
        int i = ti0 + k*4;
        tl[i][tj] = src[(size_t)(c0+i)*R + r0 + tj];
    }
    __syncthreads();
    #pragma unroll
    for (int k=0;k<16;k++){
        int j = ti0 + k*4;
        dst[(size_t)(r0+j)*CO + c0 + tj] = tl[tj][j];
    }
}

// ================= conv1 via MFMA (bf16 implicit GEMM) =================
// B-reuse + XCD-swizzle: block = (spatial, kq) with blk%8 == spatial%8 (same-XCD for shared lines).
// 4 waves = co-quarters; each wave computes 2 co-tiles (co0, co0+16) reusing one B-frag per tap.
// grid 896 = 8 * 4 * 28 (spatial = shi*8+s8 < 220, else exit). raw1: 4 kq-split buffers.
__global__ __launch_bounds__(256) void k_conv1m(const __hip_bfloat16* __restrict__ I0cl,
                                                const __hip_bfloat16* __restrict__ wT1b,
                                                float* __restrict__ raw1){
    int blk = blockIdx.x;
    int s8 = blk & 7; int rest = blk >> 3;
    int kq = rest & 3; int shi = rest >> 2;
    int spatial = shi*8 + s8;
    if (spatial >= 220) return;
    int oh = spatial % 11; int r2 = spatial / 11;
    int od = r2 % 10; int b = r2 / 10;
    int wave = threadIdx.x >> 6, lane = threadIdx.x & 63;
    int col = lane & 15, quad = lane >> 4;
    int co0 = wave*32;
    int ci_base = kq*32 + quad*8;
    f32x4 acc0 = {0.f,0.f,0.f,0.f};
    f32x4 acc1 = {0.f,0.f,0.f,0.f};
    const __hip_bfloat16* Bb = I0cl + (size_t)b*21*23*24*128 + (2*col)*128 + ci_base;
    const __hip_bfloat16* Ab = wT1b + (size_t)(co0 + col)*128 + ci_base;
    #pragma unroll 3
    for (int tap=0; tap<27; tap++){
        int kd = tap/9, kh = (tap/3)%3, kw = tap%3;
        int d = 2*od + kd, h = 2*oh + kh;     // padded indices
        const __hip_bfloat16* bp = Bb + ((size_t)(d*23 + h)*24 + kw)*128;
        const __hip_bfloat16* ap = Ab + (size_t)tap*16384;
        bf16x8 b0 = *(const bf16x8*)bp;
        bf16x8 a0 = *(const bf16x8*)ap;
        bf16x8 a1 = *(const bf16x8*)(ap + 2048);   // co + 16
        acc0 = __builtin_amdgcn_mfma_f32_16x16x32_bf16(a0, b0, acc0, 0, 0, 0);
        acc1 = __builtin_amdgcn_mfma_f32_16x16x32_bf16(a1, b0, acc1, 0, 0, 0);
    }
    if (col < 11){
        float* rb = raw1 + (size_t)kq*309760;
        #pragma unroll
        for (int r=0;r<4;r++){
            int co = co0 + quad*4 + r;
            rb[(((size_t)(b*128+co)*10 + od)*11 + oh)*11 + col] = acc0[r];
        }
        #pragma unroll
        for (int r=0;r<4;r++){
            int co = co0 + 16 + quad*4 + r;
            rb[(((size_t)(b*128+co)*10 + od)*11 + oh)*11 + col] = acc1[r];
        }
    }
}

// stats for conv1 (zero background), sums 4 K-split buffers
__global__ __launch_bounds__(256) void k_stats_c1(const float* __restrict__ raw1, const float* __restrict__ cb,
                                                  const float* __restrict__ cg, const float* __restrict__ cbe,
                                                  float* __restrict__ ACb1){
    int co = blockIdx.x;
    float s=0, ss=0;
    for (int b=0;b<2;b++){
        size_t base = ((size_t)(b*128+co))*1210;
        for (int i=threadIdx.x; i<1210; i+=256){
            float v = raw1[base+i] + raw1[309760+base+i] + raw1[2*309760+base+i] + raw1[3*309760+base+i];
            s+=v; ss+=v*v;
        }
    }
    __shared__ float sh1[256], sh2[256];
    sh1[threadIdx.x]=s; sh2[threadIdx.x]=ss; __syncthreads();
    for (int st=128; st>0; st>>=1){
        if (threadIdx.x<st){ sh1[threadIdx.x]+=sh1[threadIdx.x+st]; sh2[threadIdx.x]+=sh2[threadIdx.x+st]; }
        __syncthreads();
    }
    if (threadIdx.x==0){
        float bias = cb[co];
        const float N = 81920.f;   // 2*10*64*64
        float sum_y = sh1[0] + N*bias;
        float ssq_y = sh2[0] + 2.f*bias*sh1[0] + N*bias*bias;
        float m = sum_y/N;
        float var = ssq_y/N - m*m;
        float A = cg[co]*rsqrtf(var+EPS);
        float C = cbe[co] - m*A;
        ACb1[co]=A; ACb1[128+co]=C;
        ACb1[256+co]=fmaxf(bias*A + C, 0.f);  // bg1
    }
}

// I1p[b][ci][11][13][16]
__global__ void k_fill_I1(const float* __restrict__ raw1, const float* __restrict__ ACb1,
                          const float* __restrict__ cb, float* __restrict__ I1p){
    int i = blockIdx.x*blockDim.x + threadIdx.x;   // grid exactly 585,728
    int wpad = i % 16; int r = i / 16;
    int hpad = r % 13; r /= 13;
    int dpad = r % 11; r /= 11;
    int ci = r % 128; int b = r / 128;
    float val;
    if (dpad==0 || hpad==0 || wpad==0 || wpad>12) val = 0.f;
    else {
        int d = dpad-1, h = hpad-1, w = wpad-1;
        if (h < 11 && w < 11){
            size_t idx = (((size_t)(b*128+ci)*10 + d)*11 + h)*11 + w;
            float raw = raw1[idx] + raw1[309760+idx] + raw1[2*309760+idx] + raw1[3*309760+idx];
            val = fmaxf((raw + cb[ci])*ACb1[ci] + ACb1[128+ci], 0.f);
        } else val = ACb1[256+ci];
    }
    I1p[i] = val;
}

// conv2 background class constants: bgraw2[o][8]; coalesced via wT2
__global__ __launch_bounds__(256) void k_bg2(const float* __restrict__ wT2, const float* __restrict__ ACb1,
                                             float* __restrict__ bgraw2){
    int o = threadIdx.x;
    int ci0 = blockIdx.x*8;
    float acc[8];
    #pragma unroll
    for (int c=0;c<8;c++) acc[c]=0.f;
    for (int ci=ci0; ci<ci0+8; ci++){
        float w[27];
        const float* wp = wT2 + (size_t)ci*27*256 + o;
        #pragma unroll
        for (int t=0;t<27;t++) w[t] = wp[t*256];
        float bg = ACb1[256+ci];
        float sw0[9], sw1[9];
        #pragma unroll
        for (int t9=0;t9<9;t9++){ sw1[t9]=w[3*t9+1]+w[3*t9+2]; sw0[t9]=w[3*t9]+sw1[t9]; }
        #pragma unroll
        for (int cls=0; cls<8; cls++){
            const int d0=(cls>>2)&1, h0=(cls>>1)&1, w0=cls&1;
            float ws=0.f;
            #pragma unroll
            for (int kd=0;kd<3;kd++){
                if (d0 && kd==0) continue;
                #pragma unroll
                for (int kh=0;kh<3;kh++){
                    if (h0 && kh==0) continue;
                    ws += w0 ? sw1[kd*3+kh] : sw0[kd*3+kh];
                }
            }
            acc[cls] += bg*ws;
        }
    }
    #pragma unroll
    for (int cls=0;cls<8;cls++) atomicAdd(&bgraw2[o*8+cls], acc[cls]);
}

// conv2: grid 960 = ((b*5+od)*6+oh)*16+ciq ; 256 thr = 4 waves x 2 ci; LDS reduce -> store buf[ciq]
__global__ __launch_bounds__(256) void k_conv2(const float* __restrict__ I1p, const float* __restrict__ wT2,
                                               float* __restrict__ raw2){
    int blk = blockIdx.x;
    int ciq = blk & 15; blk >>= 4;
    int oh = blk % 6; blk /= 6;
    int od = blk % 5; int b = blk / 5;
    int wave = threadIdx.x >> 6, lane = threadIdx.x & 63;
    float acc[4][6];
    #pragma unroll
    for (int q=0;q<4;q++)
        #pragma unroll
        for (int i=0;i<6;i++) acc[q][i]=0.f;
    int ci0 = ciq*8 + wave*2;
    for (int ci = ci0; ci < ci0+2; ci++){
        const float* base = I1p + ((size_t)(b*128+ci)*11 + 2*od)*208 + (2*oh)*16;
        const float* wp0 = wT2 + (size_t)ci*27*256 + lane;
        #pragma unroll
        for (int kd=0;kd<3;kd++){
            #pragma unroll
            for (int kh=0;kh<3;kh++){
                float row[16];
                const float4* rp = (const float4*)(base + kd*208 + kh*16);
                #pragma unroll
                for (int i=0;i<4;i++){ float4 t=rp[i]; row[4*i]=t.x; row[4*i+1]=t.y; row[4*i+2]=t.z; row[4*i+3]=t.w; }
                const float* wp = wp0 + (kd*3+kh)*3*256;
                #pragma unroll
                for (int kw=0;kw<3;kw++){
                    float w0=wp[kw*256], w1=wp[kw*256+64], w2v=wp[kw*256+128], w3=wp[kw*256+192];
                    #pragma unroll
                    for (int ow=0;ow<6;ow++){
                        float x = row[2*ow+kw];
                        acc[0][ow]+=x*w0; acc[1][ow]+=x*w1; acc[2][ow]+=x*w2v; acc[3][ow]+=x*w3;
                    }
                }
            }
        }
    }
    __shared__ float red[4*1540];
    #pragma unroll
    for (int q=0;q<4;q++)
        #pragma unroll
        for (int ow=0;ow<6;ow++) red[wave*1540 + lane*24 + q*6 + ow] = acc[q][ow];
    __syncthreads();
    float* rb = raw2 + (size_t)ciq*92160;
    for (int idx = threadIdx.x; idx < 1536; idx += 256){
        int lane2 = idx/24, j = idx%24;
        float s = red[0*1540 + lane2*24 + j] + red[1*1540 + lane2*24 + j]
                + red[2*1540 + lane2*24 + j] + red[3*1540 + lane2*24 + j];
        int q = j/6, ow = j%6;
        int co = q*64 + lane2;
        rb[(((size_t)(b*256+co)*5 + od)*6 + oh)*6 + ow] = s;
    }
}

// conv2 BN stats from raw interior (16 buffers) + analytic background class counts
__global__ __launch_bounds__(64) void k_stats_c2(const float* __restrict__ raw2, const float* __restrict__ bgraw2,
                                                 const float* __restrict__ cb2, const float* __restrict__ cg2,
                                                 const float* __restrict__ cbe2, float* __restrict__ ACb2){
    int o = blockIdx.x;
    int lane = threadIdx.x;
    float s=0.f, ss=0.f;
    for (int idx=lane; idx<360; idx+=64){
        int b = idx/180; int p = idx%180;
        int d = p/36; int rem = p%36; int h = rem/6; int w = rem%6;
        size_t base = (((size_t)(b*256+o)*5 + d)*6 + h)*6 + w;
        float v = 0.f;
        #pragma unroll
        for (int q=0;q<16;q++) v += raw2[q*92160+base];
        s += v; ss += v*v;
    }
    #pragma unroll
    for (int off=32; off>0; off>>=1){ s += __shfl_down(s,off); ss += __shfl_down(ss,off); }
    if (lane==0){
        const int n2[8] = {3744,104,104,0,936,26,26,0};   // per batch; x2 batches
        float bgv[8];
        #pragma unroll
        for (int c=0;c<8;c++){ bgv[c]=bgraw2[o*8+c]; s += 2.f*n2[c]*bgv[c]; ss += 2.f*n2[c]*bgv[c]*bgv[c]; }
        const float N = 10240.f;
        float b = cb2[o];
        float sum_y = s + N*b;
        float ssq_y = ss + 2.f*b*s + N*b*b;
        float m = sum_y/N;
        float var = ssq_y/N - m*m;
        float A = cg2[o]*rsqrtf(var+EPS); float C = cbe2[o] - m*A;
        ACb2[o]=A; ACb2[256+o]=C;
        for (int c=0;c<8;c++) ACb2[512+o*8+c] = fmaxf((bgv[c]+b)*A + C, 0.f);
    }
}

// I2p[b][ci][7][9][12]
__global__ void k_fill_I2(const float* __restrict__ raw2, const float* __restrict__ ACb2,
                          const float* __restrict__ cb2, float* __restrict__ I2p){
    int i = blockIdx.x*blockDim.x + threadIdx.x;   // grid exactly 387,072
    int wpad = i % 12; int r = i / 12;
    int hpad = r % 9; r /= 9;
    int dpad = r % 7; r /= 7;
    int ci = r % 256; int b = r / 256;
    float val;
    if (dpad==0 || dpad==6 || hpad==0 || wpad==0 || wpad>8) val = 0.f;
    else {
        int d = dpad-1, h = hpad-1, w = wpad-1;
        if (h<6 && w<6){
            size_t idx = (((size_t)(b*256+ci)*5 + d)*6 + h)*6 + w;
            float raw = 0.f;
            #pragma unroll
            for (int q=0;q<16;q++) raw += raw2[q*92160+idx];
            val = fmaxf((raw + cb2[ci])*ACb2[ci] + ACb2[256+ci], 0.f);
        } else {
            int cls = ((d==0)?4:0) | ((h==0)?2:0) | ((w==0)?1:0);
            val = ACb2[512 + ci*8 + cls];
        }
    }
    I2p[i] = val;
}

// conv3 background classes: bgraw3[o][12]; coalesced via wT3
__global__ __launch_bounds__(256) void k_bg3(const float* __restrict__ wT3, const float* __restrict__ ACb2,
                                             float* __restrict__ bgraw3){
    int o = threadIdx.x;
    int ci0 = blockIdx.x*8;
    float acc[12];
    #pragma unroll
    for (int c=0;c<12;c++) acc[c]=0.f;
    for (int ci=ci0; ci<ci0+8; ci++){
        float w[27];
        const float* wp = wT3 + (size_t)ci*27*256 + o;
        #pragma unroll
        for (int t=0;t<27;t++) w[t] = wp[t*256];
        const float* bg = ACb2 + 512 + ci*8;
        float bgv[8];
        #pragma unroll
        for (int q=0;q<8;q++) bgv[q]=bg[q];
        #pragma unroll
        for (int c=0;c<12;c++){
            const int odc = c>>2; const int h0 = (c>>1)&1; const int w0 = c&1;
            float sum = 0.f;
            #pragma unroll
            for (int kd=0;kd<3;kd++){
                const int d = 2*odc-1+kd; if (d<0||d>=5) continue;
                const int db = (d==0)?4:0;
                #pragma unroll
                for (int kh=0;kh<3;kh++){
                    if (h0 && kh==0) continue;
                    const int hb = (h0 && kh==1)?2:0;
                    #pragma unroll
                    for (int kw=0;kw<3;kw++){
                        if (w0 && kw==0) continue;
                        const int wb = (w0 && kw==1)?1:0;
                        sum += bgv[db|hb|wb]*w[(kd*3+kh)*3+kw];
                    }
                }
            }
            acc[c] += sum;
        }
    }
    #pragma unroll
    for (int c=0;c<12;c++) atomicAdd(&bgraw3[o*12+c], acc[c]);
}

// conv3: grid 768 = ((b*3+od)*4+oh)*32+ciq ; 256 thr = 4 waves x 2 ci; LDS reduce -> store buf[ciq]
__global__ __launch_bounds__(256) void k_conv3(const float* __restrict__ I2p, const float* __restrict__ wT3,
                                               float* __restrict__ raw3){
    int blk = blockIdx.x;
    int ciq = blk & 31; blk >>= 5;
    int oh = blk % 4; blk /= 4;
    int od = blk % 3; int b = blk / 3;
    int wave = threadIdx.x >> 6, lane = threadIdx.x & 63;
    float acc[4][4];
    #pragma unroll
    for (int q=0;q<4;q++)
        #pragma unroll
        for (int i=0;i<4;i++) acc[q][i]=0.f;
    int ci0 = ciq*8 + wave*2;
    for (int ci = ci0; ci < ci0+2; ci++){
        const float* base = I2p + ((size_t)(b*256+ci)*7 + 2*od)*108 + (2*oh)*12;
        const float* wp0 = wT3 + (size_t)ci*27*256 + lane;
        #pragma unroll
        for (int kd=0;kd<3;kd++){
            #pragma unroll
            for (int kh=0;kh<3;kh++){
                float row[12];
                const float4* rp = (const float4*)(base + kd*108 + kh*12);
                #pragma unroll
                for (int i=0;i<3;i++){ float4 t=rp[i]; row[4*i]=t.x; row[4*i+1]=t.y; row[4*i+2]=t.z; row[4*i+3]=t.w; }
                const float* wp = wp0 + (kd*3+kh)*3*256;
                #pragma unroll
                for (int kw=0;kw<3;kw++){
                    float w0=wp[kw*256], w1=wp[kw*256+64], w2v=wp[kw*256+128], w3=wp[kw*256+192];
                    #pragma unroll
                    for (int ow=0;ow<4;ow++){
                        float x = row[2*ow+kw];
                        acc[0][ow]+=x*w0; acc[1][ow]+=x*w1; acc[2][ow]+=x*w2v; acc[3][ow]+=x*w3;
                    }
                }
            }
        }
    }
    __shared__ float red[4*1028];
    #pragma unroll
    for (int q=0;q<4;q++)
        #pragma unroll
        for (int ow=0;ow<4;ow++) red[wave*1028 + lane*16 + q*4 + ow] = acc[q][ow];
    __syncthreads();
    float* rb = raw3 + (size_t)ciq*24576;
    for (int idx = threadIdx.x; idx < 1024; idx += 256){
        int lane2 = idx/16, j = idx%16;
        float s = red[0*1028 + lane2*16 + j] + red[1*1028 + lane2*16 + j]
                + red[2*1028 + lane2*16 + j] + red[3*1028 + lane2*16 + j];
        int q = j/4, ow = j%4;
        int co = q*64 + lane2;
        rb[(((size_t)(b*256+co)*3 + od)*4 + oh)*4 + ow] = s;
    }
}

// conv3 BN stats from raw interior (32 buffers) + analytic class counts
__global__ __launch_bounds__(64) void k_stats_c3(const float* __restrict__ raw3, const float* __restrict__ bgraw3,
                                                 const float* __restrict__ cb3, const float* __restrict__ cg3,
                                                 const float* __restrict__ cbe3, float* __restrict__ AC3){
    int o = blockIdx.x;
    int lane = threadIdx.x;
    float s=0.f, ss=0.f;
    for (int idx=lane; idx<96; idx+=64){
        int b = idx/48; int p = idx%48;
        int d = p/16; int rem = p%16; int h = rem/4; int w = rem%4;
        size_t base = (((size_t)(b*256+o)*3 + d)*4 + h)*4 + w;
        float v = 0.f;
        #pragma unroll
        for (int q=0;q<32;q++) v += raw3[q*24576+base];
        s += v; ss += v*v;
    }
    #pragma unroll
    for (int off=32; off>0; off>>=1){ s += __shfl_down(s,off); ss += __shfl_down(ss,off); }
    if (lane==0){
        const int n3hw[4] = {216,12,12,0};   // per (b,od)
        for (int c=0;c<12;c++){
            float bg = bgraw3[o*12+c];
            float n = 2.f*n3hw[c&3];
            s += n*bg; ss += n*bg*bg;
        }
        const float N = 1536.f;
        float b = cb3[o];
        float sum_y = s + N*b;
        float ssq_y = ss + 2.f*b*s + N*b*b;
        float m = sum_y/N;
        float var = ssq_y/N - m*m;
        float A = cg3[o]*rsqrtf(var+EPS);
        AC3[o]=A; AC3[256+o]=cbe3[o] - m*A;
    }
}

// final output directly from raw3/bg3
__global__ void k_final(const float* __restrict__ raw3, const float* __restrict__ bgraw3,
                        const float* __restrict__ cb3, const float* __restrict__ AC3,
                        float* __restrict__ out){
    int i = blockIdx.x*blockDim.x + threadIdx.x;
    if (i >= 2*256*3*16*16) return;
    int ow = i % 16; int r = i / 16;
    int oh = r % 16; r /= 16;
    int od = r % 3; r /= 3;
    int o = r % 256; int b = r / 256;
    float v;
    if (oh<4 && ow<4){
        size_t base = (((size_t)(b*256+o)*3 + od)*4 + oh)*4 + ow;
        v = 0.f;
        #pragma unroll
        for (int q=0;q<32;q++) v += raw3[q*24576+base];
    } else {
        v = bgraw3[o*12 + od*4 + ((oh==0)?2:0) + ((ow==0)?1:0)];
    }
    out[i] = fmaxf((v + cb3[o])*AC3[o] + AC3[256+o], 0.f);
}

// ================= launch =================

extern "C" void kernel_launch(void* const* d_in, const int* in_sizes, int n_in,
                              void* d_out, int out_size, void* d_ws, size_t ws_size,
                              hipStream_t stream) {
    const float* vf    = (const float*)d_in[0];
    const int*   coords= (const int*)d_in[1];
    const float* w1    = (const float*)d_in[5];
    const float* b1    = (const float*)d_in[6];
    const float* g1    = (const float*)d_in[7];
    const float* be1   = (const float*)d_in[8];
    const float* w2    = (const float*)d_in[9];
    const float* b2    = (const float*)d_in[10];
    const float* g2    = (const float*)d_in[11];
    const float* be2   = (const float*)d_in[12];
    const float* cw1   = (const float*)d_in[13];
    const float* cb1   = (const float*)d_in[14];
    const float* cg1   = (const float*)d_in[15];
    const float* cbe1  = (const float*)d_in[16];
    const float* cw2   = (const float*)d_in[17];
    const float* cb2   = (const float*)d_in[18];
    const float* cg2   = (const float*)d_in[19];
    const float* cbe2  = (const float*)d_in[20];
    const float* cw3   = (const float*)d_in[21];
    const float* cb3   = (const float*)d_in[22];
    const float* cg3   = (const float*)d_in[23];
    const float* cbe3  = (const float*)d_in[24];
    float* out = (float*)d_out;
    float* ws  = (float*)d_ws;
    __hip_bfloat16* I0cl = (__hip_bfloat16*)(ws + OFF_I0CL);
    __hip_bfloat16* wT1b = (__hip_bfloat16*)(ws + OFF_WT1B);

    hipMemsetAsync(ws + OFF_BG2, 0,    5120*4, stream);        // BG2 + BG3
    hipMemsetAsync(ws + OFF_WIN, 0xFF, 16000*4, stream);
    hipMemsetAsync(ws + OFF_I0CL, 0, 1485824ull*4, stream);    // bf16 I0cl (incl slack)

    k_t_tile<<<777,256,0,stream>>>(cw2, cw3, w2, cw1, ws+OFF_WT2, ws+OFF_WT3, ws+OFF_W2T, wT1b);
    k_stats_x<<<750,256,0,stream>>>(vf, ws+OFF_SXP);
    k_red_sx<<<20,256,0,stream>>>(ws+OFF_SXP, ws+OFF_SX);
    k_ac1<<<1,64,0,stream>>>(ws+OFF_SX, w1,b1,g1,be1, ws+OFF_AC1);
    k_vfe1<<<6000,256,0,stream>>>(vf, w1, ws+OFF_AC1, ws+OFF_F1);
    k_stats_f1<<<256,256,0,stream>>>(ws+OFF_F1, ws+OFF_MSTP);
    k_red_mst<<<65,64,0,stream>>>(ws+OFF_MSTP, ws+OFF_MST);
    k_ac2<<<128,64,0,stream>>>(ws+OFF_MST, w2,b2,g2,be2, ws+OFF_AC2);
    k_scatter<<<94,256,0,stream>>>(coords, (int*)(ws+OFF_WIN));
    k_I0<<<800,256,0,stream>>>((int*)(ws+OFF_WIN), ws+OFF_F1, ws+OFF_W2T, ws+OFF_AC2, I0cl);
    k_conv1m<<<896,256,0,stream>>>(I0cl, wT1b, ws+OFF_RAW1);
    k_stats_c1<<<128,256,0,stream>>>(ws+OFF_RAW1, cb1,cg1,cbe1, ws+OFF_ACB1);
    k_fill_I1<<<2288,256,0,stream>>>(ws+OFF_RAW1, ws+OFF_ACB1, cb1, ws+OFF_I1);
    k_bg2<<<16,256,0,stream>>>(ws+OFF_WT2, ws+OFF_ACB1, ws+OFF_BG2);
    k_conv2<<<960,256,0,stream>>>(ws+OFF_I1, ws+OFF_WT2, ws+OFF_RAW2);
    k_stats_c2<<<256,64,0,stream>>>(ws+OFF_RAW2, ws+OFF_BG2, cb2, cg2, cbe2, ws+OFF_ACB2);
    k_fill_I2<<<1512,256,0,stream>>>(ws+OFF_RAW2, ws+OFF_ACB2, cb2, ws+OFF_I2);
    k_bg3<<<32,256,0,stream>>>(ws+OFF_WT3, ws+OFF_ACB2, ws+OFF_BG3);
    k_conv3<<<768,256,0,stream>>>(ws+OFF_I2, ws+OFF_WT3, ws+OFF_RAW3);
    k_stats_c3<<<256,64,0,stream>>>(ws+OFF_RAW3, ws+OFF_BG3, cb3, cg3, cbe3, ws+OFF_AC3);
    k_final<<<1536,256,0,stream>>>(ws+OFF_RAW3, ws+OFF_BG3, cb3, ws+OFF_AC3, out);
}